// Round 9
// baseline (383.030 us; speedup 1.0000x reference)
//
#include <hip/hip_runtime.h>
#include <hip/hip_bf16.h>

typedef _Float16 f16;
typedef _Float16 f16x4 __attribute__((ext_vector_type(4)));
typedef _Float16 f16x8 __attribute__((ext_vector_type(8)));
typedef float f32x4 __attribute__((ext_vector_type(4)));

#define DEV static __device__ __forceinline__

DEV void gld_lds16(const void* g, void* l) {
  __builtin_amdgcn_global_load_lds(
      (const __attribute__((address_space(1))) void*)g,
      (__attribute__((address_space(3))) void*)l, 16, 0, 0);
}

DEV float fast_tanh(float x) {
  float e = __expf(2.0f * x);
  return 1.0f - 2.0f / (e + 1.0f);
}

DEV int xcd_swizzle(int raw, int nwg) {
  return ((nwg & 7) == 0) ? ((raw & 7) * (nwg >> 3) + (raw >> 3)) : raw;
}

// ---------------- x (f32) -> xh (f16) ----------------
__global__ __launch_bounds__(256) void k_cvt_x(const float* __restrict__ x,
                                               f16* __restrict__ xh, long n) {
  long i0 = ((long)blockIdx.x * 256 + threadIdx.x) * 4;
  long stride = (long)gridDim.x * 1024;
  for (long i = i0; i < n; i += stride) {
    const float4 v = *(const float4*)(x + i);
    f16x4 h;
    h.x = (f16)v.x; h.y = (f16)v.y; h.z = (f16)v.z; h.w = (f16)v.w;
    *(f16x4*)(xh + i) = h;
  }
}

// ---------------- W [E][K][N] f32 -> Wt [E][N][K] f16, optional col-scale 1/std[k]
__global__ __launch_bounds__(256) void k_transpose(const float* __restrict__ in,
                                                   f16* __restrict__ out,
                                                   const float* __restrict__ stdv,
                                                   int K_, int N_) {
  __shared__ float tile[32][33];
  const int e = blockIdx.z;
  const float* ine = in + (long)e * K_ * N_;
  f16* oute = out + (long)e * K_ * N_;
  const int n0 = blockIdx.x * 32, k0 = blockIdx.y * 32;
  const int tx = threadIdx.x, ty = threadIdx.y;
#pragma unroll
  for (int j = 0; j < 4; j++)
    tile[ty + j * 8][tx] = ine[(long)(k0 + ty + j * 8) * N_ + n0 + tx];
  __syncthreads();
  const float rs = stdv ? 1.0f / stdv[(long)e * K_ + k0 + tx] : 1.0f;
#pragma unroll
  for (int j = 0; j < 4; j++)
    oute[(long)(n0 + ty + j * 8) * K_ + k0 + tx] = (f16)(tile[tx][ty + j * 8] * rs);
}

// ---------------- corrected bias: outb[e][h] = b[e][h] - sum_s (mean/std)[e][s]*W[e][s][h]
__global__ __launch_bounds__(1024) void k_bias_corr(const float* __restrict__ W,
                                                    const float* __restrict__ b,
                                                    const float* __restrict__ mean,
                                                    const float* __restrict__ stdv,
                                                    float* __restrict__ outb,
                                                    int S_, int H_) {
  __shared__ float red[16][64];
  const int e = blockIdx.y;
  const float* We = W + (long)e * S_ * H_;
  const float* me = mean + (long)e * S_;
  const float* se = stdv + (long)e * S_;
  const int h = blockIdx.x * 64 + threadIdx.x;
  const int sl = threadIdx.y;
  float acc = 0.0f;
#pragma unroll 4
  for (int s = sl; s < S_; s += 16) acc += (me[s] / se[s]) * We[(long)s * H_ + h];
  red[sl][threadIdx.x] = acc;
  __syncthreads();
  if (sl == 0) {
    float a = 0.0f;
#pragma unroll
    for (int j = 0; j < 16; j++) a += red[j][threadIdx.x];
    outb[(long)e * H_ + h] = b[(long)e * H_ + h] - a;
  }
}

// ---------------- 128x128 GEMM, BK=64, SINGLE-buffered 32 KiB LDS (m97 structure).
// Per K-step: stage (8x gld_lds16) -> barrier (drains vmcnt) -> 32 MFMA -> barrier.
// Cross-block TLP (4-5 blocks/CU by LDS/VGPR) provides the pipelining.
// Swizzle (R4-verified, 0 conflicts): physical chunk = logical ^ (row&7);
// inverse applied on the per-lane global source address (rule #21).
// C = tanh(A@Bt^T + bias) [* gwScale[row, e0+z]]. K % 64 == 0.
__global__ __launch_bounds__(256) void k_gemm_sb(
    const f16* __restrict__ A, const f16* __restrict__ Bt,
    const float* __restrict__ bias, f16* __restrict__ C,
    const float* __restrict__ gwScale, int e0,
    int M, int K, int lda, int ldb, int ldc,
    long sA, long sB, long sBias, long sC) {
  A += (long)blockIdx.z * sA; Bt += (long)blockIdx.z * sB;
  bias += (long)blockIdx.z * sBias; C += (long)blockIdx.z * sC;
  __shared__ __align__(16) f16 As[128 * 64];
  __shared__ __align__(16) f16 Bs[128 * 64];
  const int tid = threadIdx.x, wave = tid >> 6, lane = tid & 63;
  const int nwg = gridDim.x * gridDim.y;
  const int logical = xcd_swizzle(blockIdx.y * gridDim.x + blockIdx.x, nwg);
  const int bx = logical % gridDim.x, by = logical / gridDim.x;
  const int m0 = by * 128, n0 = bx * 128;
  const int wr = wave >> 1, wc = wave & 1;
  f32x4 acc[4][4] = {};
  const int swz = (tid & 7) ^ ((tid >> 3) & 7);
  const f16* Ag = A + (long)(m0 + (tid >> 3)) * lda + swz * 8;
  const f16* Bg = Bt + (long)(n0 + (tid >> 3)) * ldb + swz * 8;
  const int wo = wave * 512;

  const int nt = K >> 6;
  for (int t = 0; t < nt; ++t) {
    const long kt = (long)t << 6;
#pragma unroll
    for (int i = 0; i < 4; i++) {
      gld_lds16(Ag + (long)i * 32 * lda + kt, &As[wo + i * 2048]);
      gld_lds16(Bg + (long)i * 32 * ldb + kt, &Bs[wo + i * 2048]);
    }
    __syncthreads();  // drains vmcnt(0): tile fully staged
#pragma unroll
    for (int kk = 0; kk < 2; kk++) {
      f16x8 af[4], bfr[4];
      const int rchunk = (kk * 4 + (lane >> 4)) ^ (lane & 7);
#pragma unroll
      for (int mi = 0; mi < 4; mi++)
        af[mi] = *(const f16x8*)&As[(wr * 64 + mi * 16 + (lane & 15)) * 64 + rchunk * 8];
#pragma unroll
      for (int ni = 0; ni < 4; ni++)
        bfr[ni] = *(const f16x8*)&Bs[(wc * 64 + ni * 16 + (lane & 15)) * 64 + rchunk * 8];
#pragma unroll
      for (int mi = 0; mi < 4; mi++)
#pragma unroll
        for (int ni = 0; ni < 4; ni++)
          acc[mi][ni] = __builtin_amdgcn_mfma_f32_16x16x32_f16(af[mi], bfr[ni], acc[mi][ni], 0, 0, 0);
    }
    __syncthreads();  // all reads done before next stage overwrites
  }

  const int r0 = (lane >> 4) * 4, cb = lane & 15;
  const int e = e0 + blockIdx.z;
#pragma unroll
  for (int ni = 0; ni < 4; ni++) {
    const int col = n0 + wc * 64 + ni * 16 + cb;
    const float bc = bias[col];
#pragma unroll
    for (int mi = 0; mi < 4; mi++) {
      const int row = m0 + wr * 64 + mi * 16 + r0;
#pragma unroll
      for (int r = 0; r < 4; r++) {
        const float gv = gwScale ? gwScale[(long)(row + r) * 4 + e] : 1.0f;
        C[(long)(row + r) * ldc + col] = (f16)(fast_tanh(acc[mi][ni][r] + bc) * gv);
      }
    }
  }
}

// ---------------- gating head: logits = h1 @ gWa + gba; softmax over 4 -> gw [B,4] f32
__global__ __launch_bounds__(256) void k_gating_head(const f16* __restrict__ h1,
                                                     const float* __restrict__ gWa,
                                                     const float* __restrict__ gba,
                                                     float* __restrict__ gw, int B_) {
  const int b = blockIdx.x * 4 + (threadIdx.x >> 6);
  const int lane = threadIdx.x & 63;
  const f16x4 hv = *(const f16x4*)&h1[(long)b * 256 + lane * 4];
  float s0 = 0, s1 = 0, s2 = 0, s3 = 0;
#pragma unroll
  for (int j = 0; j < 4; j++) {
    const float hh = (float)hv[j];
    const float4 wr4 = *(const float4*)&gWa[(lane * 4 + j) * 4];
    s0 += hh * wr4.x; s1 += hh * wr4.y; s2 += hh * wr4.z; s3 += hh * wr4.w;
  }
#pragma unroll
  for (int off = 32; off >= 1; off >>= 1) {
    s0 += __shfl_xor(s0, off);
    s1 += __shfl_xor(s1, off);
    s2 += __shfl_xor(s2, off);
    s3 += __shfl_xor(s3, off);
  }
  const float l0 = s0 + gba[0], l1 = s1 + gba[1], l2 = s2 + gba[2], l3 = s3 + gba[3];
  float mx = fmaxf(fmaxf(l0, l1), fmaxf(l2, l3));
  const float e0 = __expf(l0 - mx), e1 = __expf(l1 - mx), e2 = __expf(l2 - mx), e3 = __expf(l3 - mx);
  const float inv = 1.0f / (e0 + e1 + e2 + e3);
  if (lane == 0) {
    float4 o; o.x = e0 * inv; o.y = e1 * inv; o.z = e2 * inv; o.w = e3 * inv;
    *(float4*)&gw[(long)b * 4] = o;
  }
}

// ---------------- fused head (g==4): out = sum_e he1s_e @ Wt_e^T + (sum_e gw*eba_e)*scale
__global__ __launch_bounds__(256) void k_head_fused(const f16* __restrict__ he1,
                                                    const f16* __restrict__ Wt,
                                                    const float* __restrict__ eba,
                                                    const float* __restrict__ scale,
                                                    const float* __restrict__ gw,
                                                    float* __restrict__ out,
                                                    long sA) {
  constexpr int K = 512;
  __shared__ __align__(16) f16 As[2][64 * 64];
  __shared__ __align__(16) f16 Bs[2][64 * 64];
  const int tid = threadIdx.x, wave = tid >> 6, lane = tid & 63;
  const int bid = xcd_swizzle(blockIdx.x, gridDim.x);
  const long m0 = (long)bid * 64;
  f32x4 acc[4] = {};
  const int swz_chunk = (tid & 7) ^ ((tid >> 3) & 7);
  const f16* Ag = he1 + (m0 + tid / 8) * K + swz_chunk * 8;
  const f16* Bg = Wt + (long)(tid / 8) * K + swz_chunk * 8;
  const int wo = wave * 512;

#pragma unroll
  for (int i = 0; i < 2; i++) {
    gld_lds16(Ag + (long)i * 32 * K, &As[0][wo + i * 2048]);
    gld_lds16(Bg + (long)i * 32 * K, &Bs[0][wo + i * 2048]);
  }
  __syncthreads();
  int cur = 0;
  for (int s = 0; s < 32; ++s) {
    if (s + 1 < 32) {
      const int sn = s + 1;
      const long ae = (long)(sn >> 3) * sA + ((sn & 7) << 6);
      const long be = (long)(sn >> 3) * (64 * K) + ((sn & 7) << 6);
#pragma unroll
      for (int i = 0; i < 2; i++) {
        gld_lds16(Ag + ae + (long)i * 32 * K, &As[cur ^ 1][wo + i * 2048]);
        gld_lds16(Bg + be + (long)i * 32 * K, &Bs[cur ^ 1][wo + i * 2048]);
      }
    }
#pragma unroll
    for (int kk = 0; kk < 2; kk++) {
      const int rchunk = (kk * 4 + (lane >> 4)) ^ (lane & 7);
      const f16x8 a = *(const f16x8*)&As[cur][(wave * 16 + (lane & 15)) * 64 + rchunk * 8];
#pragma unroll
      for (int ni = 0; ni < 4; ni++) {
        const f16x8 bq = *(const f16x8*)&Bs[cur][(ni * 16 + (lane & 15)) * 64 + rchunk * 8];
        acc[ni] = __builtin_amdgcn_mfma_f32_16x16x32_f16(a, bq, acc[ni], 0, 0, 0);
      }
    }
    __syncthreads();
    cur ^= 1;
  }
  const int r0 = (lane >> 4) * 4, cb = lane & 15;
#pragma unroll
  for (int ni = 0; ni < 4; ni++) {
    const int col = ni * 16 + cb;
    const float sc = scale[col];
#pragma unroll
    for (int r = 0; r < 4; r++) {
      const long row = m0 + wave * 16 + r0 + r;
      float b4 = 0.0f;
#pragma unroll
      for (int e = 0; e < 4; e++) b4 += gw[row * 4 + e] * eba[e * 64 + col];
      out[row * 64 + col] = (acc[ni][r] + b4) * sc;
    }
  }
}

// ---------------- per-expert head (fallback path)
__global__ __launch_bounds__(256) void k_head(const f16* __restrict__ he1,
                                              const f16* __restrict__ Wt,
                                              const float* __restrict__ ebae,
                                              const float* __restrict__ scale,
                                              const float* __restrict__ gw,
                                              float* __restrict__ outa,
                                              int e0, int K,
                                              long sA, long sB, long sBias, long sC) {
  const int z = blockIdx.z;
  he1 += (long)z * sA; Wt += (long)z * sB; ebae += (long)z * sBias; outa += (long)z * sC;
  const int e = e0 + z;
  __shared__ __align__(16) f16 As[2][64 * 64];
  __shared__ __align__(16) f16 Bs[2][64 * 64];
  const int tid = threadIdx.x, wave = tid >> 6, lane = tid & 63;
  const int bid = xcd_swizzle(blockIdx.x, gridDim.x);
  const long m0 = (long)bid * 64;
  f32x4 acc[4] = {};
  const int swz_chunk = (tid & 7) ^ ((tid >> 3) & 7);
  const f16* Ag = he1 + (m0 + tid / 8) * K + swz_chunk * 8;
  const f16* Bg = Wt + (long)(tid / 8) * K + swz_chunk * 8;
  const int wo = wave * 512;
#pragma unroll
  for (int i = 0; i < 2; i++) {
    gld_lds16(Ag + (long)i * 32 * K, &As[0][wo + i * 2048]);
    gld_lds16(Bg + (long)i * 32 * K, &Bs[0][wo + i * 2048]);
  }
  __syncthreads();
  const int nt = K >> 6;
  int cur = 0;
  for (int t = 0; t < nt; ++t) {
    if (t + 1 < nt) {
      const long kt = (long)(t + 1) << 6;
#pragma unroll
      for (int i = 0; i < 2; i++) {
        gld_lds16(Ag + (long)i * 32 * K + kt, &As[cur ^ 1][wo + i * 2048]);
        gld_lds16(Bg + (long)i * 32 * K + kt, &Bs[cur ^ 1][wo + i * 2048]);
      }
    }
#pragma unroll
    for (int kk = 0; kk < 2; kk++) {
      const int rchunk = (kk * 4 + (lane >> 4)) ^ (lane & 7);
      const f16x8 a = *(const f16x8*)&As[cur][(wave * 16 + (lane & 15)) * 64 + rchunk * 8];
#pragma unroll
      for (int ni = 0; ni < 4; ni++) {
        const f16x8 bq = *(const f16x8*)&Bs[cur][(ni * 16 + (lane & 15)) * 64 + rchunk * 8];
        acc[ni] = __builtin_amdgcn_mfma_f32_16x16x32_f16(a, bq, acc[ni], 0, 0, 0);
      }
    }
    __syncthreads();
    cur ^= 1;
  }
  const int r0 = (lane >> 4) * 4, cb = lane & 15;
#pragma unroll
  for (int ni = 0; ni < 4; ni++) {
    const int col = ni * 16 + cb;
    const float sb = scale[col], bb = ebae[col];
    const long row0 = m0 + wave * 16 + r0;
#pragma unroll
    for (int r = 0; r < 4; r++) {
      const long row = row0 + r;
      outa[row * 64 + col] = (acc[ni][r] + bb) * sb * gw[row * 4 + e];
    }
  }
}

// ---------------- combine: out = sum_e a_all[e] (fallback path)
__global__ __launch_bounds__(256) void k_combine(const float* __restrict__ a_all,
                                                 float* __restrict__ out, long n) {
  long i = ((long)blockIdx.x * 256 + threadIdx.x) * 4;
  if (i < n) {
    const float4 v0 = *(const float4*)(a_all + i);
    const float4 v1 = *(const float4*)(a_all + n + i);
    const float4 v2 = *(const float4*)(a_all + 2 * n + i);
    const float4 v3 = *(const float4*)(a_all + 3 * n + i);
    float4 o;
    o.x = v0.x + v1.x + v2.x + v3.x;
    o.y = v0.y + v1.y + v2.y + v3.y;
    o.z = v0.z + v1.z + v2.z + v3.z;
    o.w = v0.w + v1.w + v2.w + v3.w;
    *(float4*)(out + i) = o;
  }
}

// ---------------- launch ----------------
extern "C" void kernel_launch(void* const* d_in, const int* in_sizes, int n_in,
                              void* d_out, int out_size, void* d_ws, size_t ws_size,
                              hipStream_t stream) {
  constexpr int Bn = 16384, S = 512, H0G = 512, H1G = 256, H0E = 1024, H1E = 512, A = 64, E = 4;
  const float* x      = (const float*)d_in[0];
  const float* g_mean = (const float*)d_in[1];
  const float* g_std  = (const float*)d_in[2];
  const float* gW0    = (const float*)d_in[3];
  const float* gb0    = (const float*)d_in[4];
  const float* gW1    = (const float*)d_in[5];
  const float* gb1    = (const float*)d_in[6];
  const float* gWa    = (const float*)d_in[7];
  const float* gba    = (const float*)d_in[8];
  const float* e_mean = (const float*)d_in[9];
  const float* e_std  = (const float*)d_in[10];
  const float* eW0    = (const float*)d_in[11];
  const float* eb0    = (const float*)d_in[12];
  const float* eW1    = (const float*)d_in[13];
  const float* eb1    = (const float*)d_in[14];
  const float* eWa    = (const float*)d_in[15];
  const float* eba    = (const float*)d_in[16];
  const float* scale  = (const float*)d_in[17];
  float* out = (float*)d_out;

  char* p = (char*)d_ws;
  auto alloc = [&](size_t bytes) { char* q = p; p += (bytes + 255) & ~(size_t)255; return q; };
  f16* xh    = (f16*)alloc((size_t)Bn * S * 2);
  float* gw  = (float*)alloc((size_t)Bn * E * 4);
  float* a_all = (float*)alloc((size_t)E * Bn * A * 4);
  f16* gW0t  = (f16*)alloc((size_t)S * H0G * 2);
  f16* gW1t  = (f16*)alloc((size_t)H0G * H1G * 2);
  f16* eW0t  = (f16*)alloc((size_t)E * S * H0E * 2);
  f16* eW1t  = (f16*)alloc((size_t)E * H0E * H1E * 2);
  f16* eWat  = (f16*)alloc((size_t)E * H1E * A * 2);
  float* gb0c = (float*)alloc((size_t)H0G * 4);
  float* eb0c = (float*)alloc((size_t)E * H0E * 4);
  const size_t base = (size_t)(p - (char*)d_ws);
  const size_t per_g = ((size_t)Bn * H0E * 2 + 256) + ((size_t)Bn * H1E * 2 + 256);
  int g = 1;
  if (ws_size >= base + 4 * per_g) g = 4;
  else if (ws_size >= base + 2 * per_g) g = 2;
  f16* he0_g = (f16*)alloc((size_t)g * Bn * H0E * 2);  // [g][Bn][1024]
  f16* he1_g = (f16*)alloc((size_t)g * Bn * H1E * 2);  // [g][Bn][512]
  f16* h0g = he0_g;  // gating scratch aliases expert scratch (stream-ordered)
  f16* h1g = he1_g;

  // prep
  k_cvt_x<<<2048, 256, 0, stream>>>(x, xh, (long)Bn * S);
  k_transpose<<<dim3(H0G / 32, S / 32, 1), dim3(32, 8), 0, stream>>>(gW0, gW0t, g_std, S, H0G);
  k_transpose<<<dim3(H1G / 32, H0G / 32, 1), dim3(32, 8), 0, stream>>>(gW1, gW1t, nullptr, H0G, H1G);
  k_transpose<<<dim3(H0E / 32, S / 32, E), dim3(32, 8), 0, stream>>>(eW0, eW0t, e_std, S, H0E);
  k_transpose<<<dim3(H1E / 32, H0E / 32, E), dim3(32, 8), 0, stream>>>(eW1, eW1t, nullptr, H0E, H1E);
  k_transpose<<<dim3(A / 32, H1E / 32, E), dim3(32, 8), 0, stream>>>(eWa, eWat, nullptr, H1E, A);
  k_bias_corr<<<dim3(H0G / 64, 1), dim3(64, 16), 0, stream>>>(gW0, gb0, g_mean, g_std, gb0c, S, H0G);
  k_bias_corr<<<dim3(H0E / 64, E), dim3(64, 16), 0, stream>>>(eW0, eb0, e_mean, e_std, eb0c, S, H0E);

  // gating trunk + softmax head (single-buffered m97-structure kernel)
  k_gemm_sb<<<dim3(H0G / 128, Bn / 128, 1), 256, 0, stream>>>(
      xh, gW0t, gb0c, h0g, nullptr, 0,
      Bn, S, S, S, H0G, 0, 0, 0, 0);
  k_gemm_sb<<<dim3(H1G / 128, Bn / 128, 1), 256, 0, stream>>>(
      h0g, gW1t, gb1, h1g, nullptr, 0,
      Bn, H0G, H0G, H0G, H1G, 0, 0, 0, 0);
  k_gating_head<<<Bn / 4, 256, 0, stream>>>(h1g, gWa, gba, gw, Bn);

  if (g == 4) {
    // expert L0: z=4, shared A (xh)
    k_gemm_sb<<<dim3(H0E / 128, Bn / 128, 4), 256, 0, stream>>>(
        xh, eW0t, eb0c, he0_g, nullptr, 0,
        Bn, S, S, S, H0E,
        0, (long)S * H0E, H0E, (long)Bn * H0E);
    // expert L1: z=4, gw pre-scale in epilogue
    k_gemm_sb<<<dim3(H1E / 128, Bn / 128, 4), 256, 0, stream>>>(
        he0_g, eW1t, eb1, he1_g, gw, 0,
        Bn, H0E, H0E, H0E, H1E,
        (long)Bn * H0E, (long)H0E * H1E, H1E, (long)Bn * H1E);
    // fused head over concat-K (4 x 512), writes out directly
    k_head_fused<<<dim3(Bn / 64), 256, 0, stream>>>(
        he1_g, eWat, eba, scale, gw, out, (long)Bn * H1E);
  } else {
    for (int e0 = 0; e0 < E; e0 += g) {
      k_gemm_sb<<<dim3(H0E / 128, Bn / 128, g), 256, 0, stream>>>(
          xh, eW0t + (size_t)e0 * S * H0E, eb0c + (size_t)e0 * H0E, he0_g, nullptr, 0,
          Bn, S, S, S, H0E,
          0, (long)S * H0E, H0E, (long)Bn * H0E);
      k_gemm_sb<<<dim3(H1E / 128, Bn / 128, g), 256, 0, stream>>>(
          he0_g, eW1t + (size_t)e0 * H0E * H1E, eb1 + (size_t)e0 * H1E, he1_g, nullptr, 0,
          Bn, H0E, H0E, H0E, H1E,
          (long)Bn * H0E, (long)H0E * H1E, H1E, (long)Bn * H1E);
      k_head<<<dim3(Bn / 64, 1, g), 256, 0, stream>>>(
          he1_g, eWat + (size_t)e0 * H1E * A, eba + (size_t)e0 * A, scale, gw,
          a_all + (size_t)e0 * Bn * A, e0, H1E,
          (long)Bn * H1E, (long)H1E * A, A, (long)Bn * A);
    }
    k_combine<<<(Bn * A) / 1024, 256, 0, stream>>>(a_all, out, (long)Bn * A);
  }
}

// Round 10
// 306.855 us; speedup vs baseline: 1.2482x; 1.2482x over previous
//
#include <hip/hip_runtime.h>
#include <hip/hip_bf16.h>

typedef _Float16 f16;
typedef _Float16 f16x4 __attribute__((ext_vector_type(4)));
typedef _Float16 f16x8 __attribute__((ext_vector_type(8)));
typedef float f32x4 __attribute__((ext_vector_type(4)));

#define DEV static __device__ __forceinline__

DEV void gld_lds16(const void* g, void* l) {
  __builtin_amdgcn_global_load_lds(
      (const __attribute__((address_space(1))) void*)g,
      (__attribute__((address_space(3))) void*)l, 16, 0, 0);
}

DEV float fast_tanh(float x) {
  float e = __expf(2.0f * x);
  return 1.0f - 2.0f / (e + 1.0f);
}

DEV int xcd_swizzle(int raw, int nwg) {
  return ((nwg & 7) == 0) ? ((raw & 7) * (nwg >> 3) + (raw >> 3)) : raw;
}

// ---------------- x (f32) -> xh (f16) ----------------
__global__ __launch_bounds__(256) void k_cvt_x(const float* __restrict__ x,
                                               f16* __restrict__ xh, long n) {
  long i0 = ((long)blockIdx.x * 256 + threadIdx.x) * 4;
  long stride = (long)gridDim.x * 1024;
  for (long i = i0; i < n; i += stride) {
    const float4 v = *(const float4*)(x + i);
    f16x4 h;
    h.x = (f16)v.x; h.y = (f16)v.y; h.z = (f16)v.z; h.w = (f16)v.w;
    *(f16x4*)(xh + i) = h;
  }
}

// ---------------- W [E][K][N] f32 -> Wt [E][N][K] f16, optional col-scale 1/std[k]
__global__ __launch_bounds__(256) void k_transpose(const float* __restrict__ in,
                                                   f16* __restrict__ out,
                                                   const float* __restrict__ stdv,
                                                   int K_, int N_) {
  __shared__ float tile[32][33];
  const int e = blockIdx.z;
  const float* ine = in + (long)e * K_ * N_;
  f16* oute = out + (long)e * K_ * N_;
  const int n0 = blockIdx.x * 32, k0 = blockIdx.y * 32;
  const int tx = threadIdx.x, ty = threadIdx.y;
#pragma unroll
  for (int j = 0; j < 4; j++)
    tile[ty + j * 8][tx] = ine[(long)(k0 + ty + j * 8) * N_ + n0 + tx];
  __syncthreads();
  const float rs = stdv ? 1.0f / stdv[(long)e * K_ + k0 + tx] : 1.0f;
#pragma unroll
  for (int j = 0; j < 4; j++)
    oute[(long)(n0 + ty + j * 8) * K_ + k0 + tx] = (f16)(tile[tx][ty + j * 8] * rs);
}

// ---------------- corrected bias: outb[e][h] = b[e][h] - sum_s (mean/std)[e][s]*W[e][s][h]
__global__ __launch_bounds__(1024) void k_bias_corr(const float* __restrict__ W,
                                                    const float* __restrict__ b,
                                                    const float* __restrict__ mean,
                                                    const float* __restrict__ stdv,
                                                    float* __restrict__ outb,
                                                    int S_, int H_) {
  __shared__ float red[16][64];
  const int e = blockIdx.y;
  const float* We = W + (long)e * S_ * H_;
  const float* me = mean + (long)e * S_;
  const float* se = stdv + (long)e * S_;
  const int h = blockIdx.x * 64 + threadIdx.x;
  const int sl = threadIdx.y;
  float acc = 0.0f;
#pragma unroll 4
  for (int s = sl; s < S_; s += 16) acc += (me[s] / se[s]) * We[(long)s * H_ + h];
  red[sl][threadIdx.x] = acc;
  __syncthreads();
  if (sl == 0) {
    float a = 0.0f;
#pragma unroll
    for (int j = 0; j < 16; j++) a += red[j][threadIdx.x];
    outb[(long)e * H_ + h] = b[(long)e * H_ + h] - a;
  }
}

// ---------------- 128x128 GEMM, BK=64, double-buffered (R4-proven structure).
// Per K-step: prefetch next tile into buf^1, compute buf, one __syncthreads.
// Swizzle (R4-verified, 0 conflicts). C = tanh(A@Bt^T + bias).
// Split C-write: cols < split -> C0 (ldc0), cols >= split -> C1 (ldc1, col-split).
__global__ __launch_bounds__(256) void k_gemm_db(
    const f16* __restrict__ A, const f16* __restrict__ Bt,
    const float* __restrict__ bias, f16* __restrict__ C0, f16* __restrict__ C1,
    int split, int M, int K, int lda, int ldb, int ldc0, int ldc1,
    long sA, long sB, long sBias, long sC) {
  A += (long)blockIdx.z * sA; Bt += (long)blockIdx.z * sB;
  bias += (long)blockIdx.z * sBias; C0 += (long)blockIdx.z * sC;
  __shared__ __align__(16) f16 As[2][128 * 64];
  __shared__ __align__(16) f16 Bs[2][128 * 64];
  const int tid = threadIdx.x, wave = tid >> 6, lane = tid & 63;
  const int nwg = gridDim.x * gridDim.y;
  const int logical = xcd_swizzle(blockIdx.y * gridDim.x + blockIdx.x, nwg);
  const int bx = logical % gridDim.x, by = logical / gridDim.x;
  const int m0 = by * 128, n0 = bx * 128;
  const int wr = wave >> 1, wc = wave & 1;
  f32x4 acc[4][4] = {};
  const int swz = (tid & 7) ^ ((tid >> 3) & 7);
  const f16* Ag = A + (long)(m0 + (tid >> 3)) * lda + swz * 8;
  const f16* Bg = Bt + (long)(n0 + (tid >> 3)) * ldb + swz * 8;
  const int wo = wave * 512;

#pragma unroll
  for (int i = 0; i < 4; i++) {
    gld_lds16(Ag + (long)i * 32 * lda, &As[0][wo + i * 2048]);
    gld_lds16(Bg + (long)i * 32 * ldb, &Bs[0][wo + i * 2048]);
  }
  __syncthreads();

  const int nt = K >> 6;
  int cur = 0;
  for (int t = 0; t < nt; ++t) {
    if (t + 1 < nt) {
      const long kt = (long)(t + 1) << 6;
#pragma unroll
      for (int i = 0; i < 4; i++) {
        gld_lds16(Ag + (long)i * 32 * lda + kt, &As[cur ^ 1][wo + i * 2048]);
        gld_lds16(Bg + (long)i * 32 * ldb + kt, &Bs[cur ^ 1][wo + i * 2048]);
      }
    }
#pragma unroll
    for (int kk = 0; kk < 2; kk++) {
      f16x8 af[4], bfr[4];
      const int rchunk = (kk * 4 + (lane >> 4)) ^ (lane & 7);
#pragma unroll
      for (int mi = 0; mi < 4; mi++)
        af[mi] = *(const f16x8*)&As[cur][(wr * 64 + mi * 16 + (lane & 15)) * 64 + rchunk * 8];
#pragma unroll
      for (int ni = 0; ni < 4; ni++)
        bfr[ni] = *(const f16x8*)&Bs[cur][(wc * 64 + ni * 16 + (lane & 15)) * 64 + rchunk * 8];
#pragma unroll
      for (int mi = 0; mi < 4; mi++)
#pragma unroll
        for (int ni = 0; ni < 4; ni++)
          acc[mi][ni] = __builtin_amdgcn_mfma_f32_16x16x32_f16(af[mi], bfr[ni], acc[mi][ni], 0, 0, 0);
    }
    __syncthreads();
    cur ^= 1;
  }

  const int r0 = (lane >> 4) * 4, cb = lane & 15;
#pragma unroll
  for (int ni = 0; ni < 4; ni++) {
    const int col = n0 + wc * 64 + ni * 16 + cb;
    const float bc = bias[col];
    const bool r1 = (col >= split);            // block-uniform (split % 128 == 0)
    f16* Cp = r1 ? C1 : C0;
    const int ld = r1 ? ldc1 : ldc0;
    const int c2 = r1 ? col - split : col;
#pragma unroll
    for (int mi = 0; mi < 4; mi++) {
      const int row = m0 + wr * 64 + mi * 16 + r0;
#pragma unroll
      for (int r = 0; r < 4; r++)
        Cp[(long)(row + r) * ld + c2] = (f16)fast_tanh(acc[mi][ni][r] + bc);
    }
  }
}

// ---------------- gating head: logits = h1 @ gWa + gba; softmax over 4 -> gw [B,4] f32
__global__ __launch_bounds__(256) void k_gating_head(const f16* __restrict__ h1,
                                                     const float* __restrict__ gWa,
                                                     const float* __restrict__ gba,
                                                     float* __restrict__ gw, int B_) {
  const int b = blockIdx.x * 4 + (threadIdx.x >> 6);
  const int lane = threadIdx.x & 63;
  const f16x4 hv = *(const f16x4*)&h1[(long)b * 256 + lane * 4];
  float s0 = 0, s1 = 0, s2 = 0, s3 = 0;
#pragma unroll
  for (int j = 0; j < 4; j++) {
    const float hh = (float)hv[j];
    const float4 wr4 = *(const float4*)&gWa[(lane * 4 + j) * 4];
    s0 += hh * wr4.x; s1 += hh * wr4.y; s2 += hh * wr4.z; s3 += hh * wr4.w;
  }
#pragma unroll
  for (int off = 32; off >= 1; off >>= 1) {
    s0 += __shfl_xor(s0, off);
    s1 += __shfl_xor(s1, off);
    s2 += __shfl_xor(s2, off);
    s3 += __shfl_xor(s3, off);
  }
  const float l0 = s0 + gba[0], l1 = s1 + gba[1], l2 = s2 + gba[2], l3 = s3 + gba[3];
  float mx = fmaxf(fmaxf(l0, l1), fmaxf(l2, l3));
  const float e0 = __expf(l0 - mx), e1 = __expf(l1 - mx), e2 = __expf(l2 - mx), e3 = __expf(l3 - mx);
  const float inv = 1.0f / (e0 + e1 + e2 + e3);
  if (lane == 0) {
    float4 o; o.x = e0 * inv; o.y = e1 * inv; o.z = e2 * inv; o.w = e3 * inv;
    *(float4*)&gw[(long)b * 4] = o;
  }
}

// ---------------- fused head (g==4): out[b,a] = [sum_e gw[b,e]*((he1_e@Wt_e^T)[b,a]
//                  + eba[e,a])] * scale[a]; gw applied in-register per expert segment.
// he1 [4][Bn][512] f16 (UNscaled), Wt [4][64][512] f16. grid Bn/64, 256 thr.
__global__ __launch_bounds__(256) void k_head2(const f16* __restrict__ he1,
                                               const f16* __restrict__ Wt,
                                               const float* __restrict__ eba,
                                               const float* __restrict__ scale,
                                               const float* __restrict__ gw,
                                               float* __restrict__ out,
                                               long sA) {
  constexpr int K = 512;
  __shared__ __align__(16) f16 As[2][64 * 64];
  __shared__ __align__(16) f16 Bs[2][64 * 64];
  const int tid = threadIdx.x, wave = tid >> 6, lane = tid & 63;
  const int bid = xcd_swizzle(blockIdx.x, gridDim.x);
  const long m0 = (long)bid * 64;
  const int swz = (tid & 7) ^ ((tid >> 3) & 7);
  const f16* Ag = he1 + (m0 + tid / 8) * K + swz * 8;
  const f16* Bg = Wt + (long)(tid / 8) * K + swz * 8;
  const int wo = wave * 512;
  const int r0 = (lane >> 4) * 4, cb = lane & 15;
  float4 gwv[4];
#pragma unroll
  for (int r = 0; r < 4; r++)
    gwv[r] = *(const float4*)&gw[(m0 + wave * 16 + r0 + r) * 4];
  f32x4 osum[4] = {};
  f32x4 acc[4] = {};

#pragma unroll
  for (int i = 0; i < 2; i++) {
    gld_lds16(Ag + (long)i * 32 * K, &As[0][wo + i * 2048]);
    gld_lds16(Bg + (long)i * 32 * K, &Bs[0][wo + i * 2048]);
  }
  __syncthreads();
  int cur = 0;
#pragma unroll
  for (int e = 0; e < 4; e++) {
    for (int kt = 0; kt < 8; ++kt) {
      const int s = e * 8 + kt;
      if (s + 1 < 32) {
        const int sn = s + 1;
        const long ae = (long)(sn >> 3) * sA + ((sn & 7) << 6);
        const long be = (long)(sn >> 3) * (64 * K) + ((sn & 7) << 6);
#pragma unroll
        for (int i = 0; i < 2; i++) {
          gld_lds16(Ag + ae + (long)i * 32 * K, &As[cur ^ 1][wo + i * 2048]);
          gld_lds16(Bg + be + (long)i * 32 * K, &Bs[cur ^ 1][wo + i * 2048]);
        }
      }
#pragma unroll
      for (int kk = 0; kk < 2; kk++) {
        const int rchunk = (kk * 4 + (lane >> 4)) ^ (lane & 7);
        const f16x8 a = *(const f16x8*)&As[cur][(wave * 16 + (lane & 15)) * 64 + rchunk * 8];
#pragma unroll
        for (int ni = 0; ni < 4; ni++) {
          const f16x8 bq = *(const f16x8*)&Bs[cur][(ni * 16 + (lane & 15)) * 64 + rchunk * 8];
          acc[ni] = __builtin_amdgcn_mfma_f32_16x16x32_f16(a, bq, acc[ni], 0, 0, 0);
        }
      }
      __syncthreads();
      cur ^= 1;
    }
    // fold expert e's contribution with static-index gw component (rule #20)
#pragma unroll
    for (int ni = 0; ni < 4; ni++)
#pragma unroll
      for (int r = 0; r < 4; r++) {
        const float ge = (e == 0) ? gwv[r].x : (e == 1) ? gwv[r].y
                        : (e == 2) ? gwv[r].z : gwv[r].w;
        osum[ni][r] += ge * acc[ni][r];
        acc[ni][r] = 0.0f;
      }
  }

#pragma unroll
  for (int ni = 0; ni < 4; ni++) {
    const int col = ni * 16 + cb;
    const float sc = scale[col];
#pragma unroll
    for (int r = 0; r < 4; r++) {
      const long row = m0 + wave * 16 + r0 + r;
      const float b4 = gwv[r].x * eba[col] + gwv[r].y * eba[64 + col] +
                       gwv[r].z * eba[128 + col] + gwv[r].w * eba[192 + col];
      out[row * 64 + col] = (osum[ni][r] + b4) * sc;
    }
  }
}

// ---------------- per-expert head (fallback path)
__global__ __launch_bounds__(256) void k_head(const f16* __restrict__ he1,
                                              const f16* __restrict__ Wt,
                                              const float* __restrict__ ebae,
                                              const float* __restrict__ scale,
                                              const float* __restrict__ gw,
                                              float* __restrict__ outa,
                                              int e0, int K,
                                              long sA, long sB, long sBias, long sC) {
  const int z = blockIdx.z;
  he1 += (long)z * sA; Wt += (long)z * sB; ebae += (long)z * sBias; outa += (long)z * sC;
  const int e = e0 + z;
  __shared__ __align__(16) f16 As[2][64 * 64];
  __shared__ __align__(16) f16 Bs[2][64 * 64];
  const int tid = threadIdx.x, wave = tid >> 6, lane = tid & 63;
  const int bid = xcd_swizzle(blockIdx.x, gridDim.x);
  const long m0 = (long)bid * 64;
  f32x4 acc[4] = {};
  const int swz = (tid & 7) ^ ((tid >> 3) & 7);
  const f16* Ag = he1 + (m0 + tid / 8) * K + swz * 8;
  const f16* Bg = Wt + (long)(tid / 8) * K + swz * 8;
  const int wo = wave * 512;
#pragma unroll
  for (int i = 0; i < 2; i++) {
    gld_lds16(Ag + (long)i * 32 * K, &As[0][wo + i * 2048]);
    gld_lds16(Bg + (long)i * 32 * K, &Bs[0][wo + i * 2048]);
  }
  __syncthreads();
  const int nt = K >> 6;
  int cur = 0;
  for (int t = 0; t < nt; ++t) {
    if (t + 1 < nt) {
      const long kt = (long)(t + 1) << 6;
#pragma unroll
      for (int i = 0; i < 2; i++) {
        gld_lds16(Ag + (long)i * 32 * K + kt, &As[cur ^ 1][wo + i * 2048]);
        gld_lds16(Bg + (long)i * 32 * K + kt, &Bs[cur ^ 1][wo + i * 2048]);
      }
    }
#pragma unroll
    for (int kk = 0; kk < 2; kk++) {
      const int rchunk = (kk * 4 + (lane >> 4)) ^ (lane & 7);
      const f16x8 a = *(const f16x8*)&As[cur][(wave * 16 + (lane & 15)) * 64 + rchunk * 8];
#pragma unroll
      for (int ni = 0; ni < 4; ni++) {
        const f16x8 bq = *(const f16x8*)&Bs[cur][(ni * 16 + (lane & 15)) * 64 + rchunk * 8];
        acc[ni] = __builtin_amdgcn_mfma_f32_16x16x32_f16(a, bq, acc[ni], 0, 0, 0);
      }
    }
    __syncthreads();
    cur ^= 1;
  }
  const int r0 = (lane >> 4) * 4, cb = lane & 15;
#pragma unroll
  for (int ni = 0; ni < 4; ni++) {
    const int col = ni * 16 + cb;
    const float sb = scale[col], bb = ebae[col];
    const long row0 = m0 + wave * 16 + r0;
#pragma unroll
    for (int r = 0; r < 4; r++) {
      const long row = row0 + r;
      outa[row * 64 + col] = (acc[ni][r] + bb) * sb * gw[row * 4 + e];
    }
  }
}

// ---------------- combine: out = sum_e a_all[e] (fallback path)
__global__ __launch_bounds__(256) void k_combine(const float* __restrict__ a_all,
                                                 float* __restrict__ out, long n) {
  long i = ((long)blockIdx.x * 256 + threadIdx.x) * 4;
  if (i < n) {
    const float4 v0 = *(const float4*)(a_all + i);
    const float4 v1 = *(const float4*)(a_all + n + i);
    const float4 v2 = *(const float4*)(a_all + 2 * n + i);
    const float4 v3 = *(const float4*)(a_all + 3 * n + i);
    float4 o;
    o.x = v0.x + v1.x + v2.x + v3.x;
    o.y = v0.y + v1.y + v2.y + v3.y;
    o.z = v0.z + v1.z + v2.z + v3.z;
    o.w = v0.w + v1.w + v2.w + v3.w;
    *(float4*)(out + i) = o;
  }
}

// ---------------- launch ----------------
extern "C" void kernel_launch(void* const* d_in, const int* in_sizes, int n_in,
                              void* d_out, int out_size, void* d_ws, size_t ws_size,
                              hipStream_t stream) {
  constexpr int Bn = 16384, S = 512, H0G = 512, H1G = 256, H0E = 1024, H1E = 512, A = 64, E = 4;
  constexpr int NCAT = H0G + E * H0E;  // 4608 merged-L0 output columns
  const float* x      = (const float*)d_in[0];
  const float* g_mean = (const float*)d_in[1];
  const float* g_std  = (const float*)d_in[2];
  const float* gW0    = (const float*)d_in[3];
  const float* gb0    = (const float*)d_in[4];
  const float* gW1    = (const float*)d_in[5];
  const float* gb1    = (const float*)d_in[6];
  const float* gWa    = (const float*)d_in[7];
  const float* gba    = (const float*)d_in[8];
  const float* e_mean = (const float*)d_in[9];
  const float* e_std  = (const float*)d_in[10];
  const float* eW0    = (const float*)d_in[11];
  const float* eb0    = (const float*)d_in[12];
  const float* eW1    = (const float*)d_in[13];
  const float* eb1    = (const float*)d_in[14];
  const float* eWa    = (const float*)d_in[15];
  const float* eba    = (const float*)d_in[16];
  const float* scale  = (const float*)d_in[17];
  float* out = (float*)d_out;

  char* p = (char*)d_ws;
  auto alloc = [&](size_t bytes) { char* q = p; p += (bytes + 255) & ~(size_t)255; return q; };
  f16* xh    = (f16*)alloc((size_t)Bn * S * 2);
  float* gw  = (float*)alloc((size_t)Bn * E * 4);
  float* a_all = (float*)alloc((size_t)E * Bn * A * 4);
  f16* wcat  = (f16*)alloc((size_t)NCAT * S * 2);      // [gW0t(512) ; eW0t(4096)] rows x K=512
  f16* gW0t  = wcat;
  f16* eW0t  = wcat + (size_t)H0G * S;
  f16* gW1t  = (f16*)alloc((size_t)H0G * H1G * 2);
  f16* eW1t  = (f16*)alloc((size_t)E * H0E * H1E * 2);
  f16* eWat  = (f16*)alloc((size_t)E * H1E * A * 2);
  float* bias_all = (float*)alloc((size_t)NCAT * 4);   // [gb0c(512) ; eb0c(4096)]
  f16* h0g   = (f16*)alloc((size_t)Bn * H0G * 2);      // gating h0 (separate: co-written with he0)
  const size_t base = (size_t)(p - (char*)d_ws);
  const size_t per_g = ((size_t)Bn * H0E * 2 + 256) + ((size_t)Bn * H1E * 2 + 256);
  int g = 1;
  if (ws_size >= base + 4 * per_g) g = 4;
  else if (ws_size >= base + 2 * per_g) g = 2;
  f16* he0_g = (f16*)alloc((size_t)g * Bn * H0E * 2);  // g=4: [Bn][4096] merged layout
  f16* he1_g = (f16*)alloc((size_t)g * Bn * H1E * 2);  // [g][Bn][512]
  f16* h1g = he1_g;  // gating h1 aliases he1 scratch (read before expert L1 writes)

  // prep
  k_cvt_x<<<2048, 256, 0, stream>>>(x, xh, (long)Bn * S);
  k_transpose<<<dim3(H0G / 32, S / 32, 1), dim3(32, 8), 0, stream>>>(gW0, gW0t, g_std, S, H0G);
  k_transpose<<<dim3(H1G / 32, H0G / 32, 1), dim3(32, 8), 0, stream>>>(gW1, gW1t, nullptr, H0G, H1G);
  k_transpose<<<dim3(H0E / 32, S / 32, E), dim3(32, 8), 0, stream>>>(eW0, eW0t, e_std, S, H0E);
  k_transpose<<<dim3(H1E / 32, H0E / 32, E), dim3(32, 8), 0, stream>>>(eW1, eW1t, nullptr, H0E, H1E);
  k_transpose<<<dim3(A / 32, H1E / 32, E), dim3(32, 8), 0, stream>>>(eWa, eWat, nullptr, H1E, A);
  k_bias_corr<<<dim3(H0G / 64, 1), dim3(64, 16), 0, stream>>>(gW0, gb0, g_mean, g_std, bias_all, S, H0G);
  k_bias_corr<<<dim3(H0E / 64, E), dim3(64, 16), 0, stream>>>(eW0, eb0, e_mean, e_std, bias_all + H0G, S, H0E);

  const int BIG = 1 << 30;
  if (g == 4) {
    // merged L0: gating h0 (cols 0..511) + all experts he0 (cols 512..4607)
    k_gemm_db<<<dim3(NCAT / 128, Bn / 128, 1), 256, 0, stream>>>(
        xh, wcat, bias_all, h0g, he0_g, H0G,
        Bn, S, S, S, H0G, E * H0E, 0, 0, 0, 0);
    // gating L1 + head
    k_gemm_db<<<dim3(H1G / 128, Bn / 128, 1), 256, 0, stream>>>(
        h0g, gW1t, gb1, h1g, nullptr, BIG,
        Bn, H0G, H0G, H0G, H1G, 0, 0, 0, 0, 0);
    k_gating_head<<<Bn / 4, 256, 0, stream>>>(h1g, gWa, gba, gw, Bn);
    // expert L1 (unscaled), z=4, A = merged he0 slice (lda=4096, z-stride 1024)
    k_gemm_db<<<dim3(H1E / 128, Bn / 128, E), 256, 0, stream>>>(
        he0_g, eW1t, eb1, he1_g, nullptr, BIG,
        Bn, H0E, E * H0E, H0E, H1E, 0,
        H0E, (long)H0E * H1E, H1E, (long)Bn * H1E);
    // fused head: applies gw per expert segment, writes out directly
    k_head2<<<dim3(Bn / 64), 256, 0, stream>>>(
        he1_g, eWat, eba, scale, gw, out, (long)Bn * H1E);
  } else {
    // gating trunk standalone
    k_gemm_db<<<dim3(H0G / 128, Bn / 128, 1), 256, 0, stream>>>(
        xh, gW0t, bias_all, h0g, nullptr, BIG,
        Bn, S, S, S, H0G, 0, 0, 0, 0, 0);
    k_gemm_db<<<dim3(H1G / 128, Bn / 128, 1), 256, 0, stream>>>(
        h0g, gW1t, gb1, h1g, nullptr, BIG,
        Bn, H0G, H0G, H0G, H1G, 0, 0, 0, 0, 0);
    k_gating_head<<<Bn / 4, 256, 0, stream>>>(h1g, gWa, gba, gw, Bn);
    for (int e0 = 0; e0 < E; e0 += g) {
      k_gemm_db<<<dim3(H0E / 128, Bn / 128, g), 256, 0, stream>>>(
          xh, eW0t + (size_t)e0 * S * H0E, bias_all + H0G + (size_t)e0 * H0E, he0_g, nullptr, BIG,
          Bn, S, S, S, H0E, 0,
          0, (long)S * H0E, H0E, (long)Bn * H0E);
      k_gemm_db<<<dim3(H1E / 128, Bn / 128, g), 256, 0, stream>>>(
          he0_g, eW1t + (size_t)e0 * H0E * H1E, eb1 + (size_t)e0 * H1E, he1_g, nullptr, BIG,
          Bn, H0E, H0E, H0E, H1E, 0,
          (long)Bn * H0E, (long)H0E * H1E, H1E, (long)Bn * H1E);
      k_head<<<dim3(Bn / 64, 1, g), 256, 0, stream>>>(
          he1_g, eWat + (size_t)e0 * H1E * A, eba + (size_t)e0 * A, scale, gw,
          a_all + (size_t)e0 * Bn * A, e0, H1E,
          (long)Bn * H1E, (long)H1E * A, A, (long)Bn * A);
    }
    k_combine<<<(Bn * A) / 1024, 256, 0, stream>>>(a_all, out, (long)Bn * A);
  }
}

// Round 11
// 296.660 us; speedup vs baseline: 1.2911x; 1.0344x over previous
//
#include <hip/hip_runtime.h>
#include <hip/hip_bf16.h>

typedef _Float16 f16;
typedef _Float16 f16x4 __attribute__((ext_vector_type(4)));
typedef _Float16 f16x8 __attribute__((ext_vector_type(8)));
typedef float f32x4 __attribute__((ext_vector_type(4)));

#define DEV static __device__ __forceinline__

DEV void gld_lds16(const void* g, void* l) {
  __builtin_amdgcn_global_load_lds(
      (const __attribute__((address_space(1))) void*)g,
      (__attribute__((address_space(3))) void*)l, 16, 0, 0);
}

DEV float fast_tanh(float x) {
  float e = __expf(2.0f * x);
  return 1.0f - 2.0f / (e + 1.0f);
}

DEV int xcd_swizzle(int raw, int nwg) {
  return ((nwg & 7) == 0) ? ((raw & 7) * (nwg >> 3) + (raw >> 3)) : raw;
}

// ---------------- x (f32) -> xh (f16) ----------------
__global__ __launch_bounds__(256) void k_cvt_x(const float* __restrict__ x,
                                               f16* __restrict__ xh, long n) {
  long i0 = ((long)blockIdx.x * 256 + threadIdx.x) * 4;
  long stride = (long)gridDim.x * 1024;
  for (long i = i0; i < n; i += stride) {
    const float4 v = *(const float4*)(x + i);
    f16x4 h;
    h.x = (f16)v.x; h.y = (f16)v.y; h.z = (f16)v.z; h.w = (f16)v.w;
    *(f16x4*)(xh + i) = h;
  }
}

// ---------------- W [E][K][N] f32 -> Wt [E][N][K] f16, optional col-scale 1/std[k]
__global__ __launch_bounds__(256) void k_transpose(const float* __restrict__ in,
                                                   f16* __restrict__ out,
                                                   const float* __restrict__ stdv,
                                                   int K_, int N_) {
  __shared__ float tile[32][33];
  const int e = blockIdx.z;
  const float* ine = in + (long)e * K_ * N_;
  f16* oute = out + (long)e * K_ * N_;
  const int n0 = blockIdx.x * 32, k0 = blockIdx.y * 32;
  const int tx = threadIdx.x, ty = threadIdx.y;
#pragma unroll
  for (int j = 0; j < 4; j++)
    tile[ty + j * 8][tx] = ine[(long)(k0 + ty + j * 8) * N_ + n0 + tx];
  __syncthreads();
  const float rs = stdv ? 1.0f / stdv[(long)e * K_ + k0 + tx] : 1.0f;
#pragma unroll
  for (int j = 0; j < 4; j++)
    oute[(long)(n0 + ty + j * 8) * K_ + k0 + tx] = (f16)(tile[tx][ty + j * 8] * rs);
}

// ---------------- corrected bias: outb[e][h] = b[e][h] - sum_s (mean/std)[e][s]*W[e][s][h]
__global__ __launch_bounds__(1024) void k_bias_corr(const float* __restrict__ W,
                                                    const float* __restrict__ b,
                                                    const float* __restrict__ mean,
                                                    const float* __restrict__ stdv,
                                                    float* __restrict__ outb,
                                                    int S_, int H_) {
  __shared__ float red[16][64];
  const int e = blockIdx.y;
  const float* We = W + (long)e * S_ * H_;
  const float* me = mean + (long)e * S_;
  const float* se = stdv + (long)e * S_;
  const int h = blockIdx.x * 64 + threadIdx.x;
  const int sl = threadIdx.y;
  float acc = 0.0f;
#pragma unroll 4
  for (int s = sl; s < S_; s += 16) acc += (me[s] / se[s]) * We[(long)s * H_ + h];
  red[sl][threadIdx.x] = acc;
  __syncthreads();
  if (sl == 0) {
    float a = 0.0f;
#pragma unroll
    for (int j = 0; j < 16; j++) a += red[j][threadIdx.x];
    outb[(long)e * H_ + h] = b[(long)e * H_ + h] - a;
  }
}

// ---------------- 128x128 GEMM, BK=64, counted-vmcnt pipeline.
// LDS (dynamic 80 KiB): A 3-deep (buf t%3), B 2-deep (buf t&1).
// Per iter t: issue STG_B(t+1) then STG_A(t+2); compute tile t;
// s_waitcnt vmcnt(4) (FIFO: retires A(t+1),B(t+1); leaves A(t+2) in flight);
// raw s_barrier. vmcnt(0) only when t+2 >= nt. Each wave waits its own loads
// before the barrier -> staged data visible block-wide next iter.
// WAR: buffer staged at iter t was last read at iter t-1 (sealed by its barrier).
// Swizzle = R4-verified (0 conflicts). C = tanh(A@Bt^T + bias). K%64==0, nt>=2.
__global__ __launch_bounds__(256) void k_gemm_cv(
    const f16* __restrict__ A, const f16* __restrict__ Bt,
    const float* __restrict__ bias, f16* __restrict__ C,
    int M, int K, int lda, int ldb, int ldc,
    long sA, long sB, long sBias, long sC) {
  A += (long)blockIdx.z * sA; Bt += (long)blockIdx.z * sB;
  bias += (long)blockIdx.z * sBias; C += (long)blockIdx.z * sC;
  extern __shared__ __align__(16) f16 lds[];  // A: 3*8192 f16, B at 24576 + 2*8192
  const int tid = threadIdx.x, wave = tid >> 6, lane = tid & 63;
  const int nwg = gridDim.x * gridDim.y;
  const int logical = xcd_swizzle(blockIdx.y * gridDim.x + blockIdx.x, nwg);
  const int bx = logical % gridDim.x, by = logical / gridDim.x;
  const int m0 = by * 128, n0 = bx * 128;
  const int wr = wave >> 1, wc = wave & 1;
  f32x4 acc[4][4] = {};
  const int swz = (tid & 7) ^ ((tid >> 3) & 7);
  const f16* Ag = A + (long)(m0 + (tid >> 3)) * lda + swz * 8;
  const f16* Bg = Bt + (long)(n0 + (tid >> 3)) * ldb + swz * 8;
  const int wo = wave * 512;

#define STG_A(bufi, tile)                                         \
  { f16* _d = lds + (bufi) * 8192 + wo;                           \
    const long _k = (long)(tile) << 6;                            \
    gld_lds16(Ag + _k, _d);                                       \
    gld_lds16(Ag + (long)32 * lda + _k, _d + 2048);               \
    gld_lds16(Ag + (long)64 * lda + _k, _d + 4096);               \
    gld_lds16(Ag + (long)96 * lda + _k, _d + 6144); }
#define STG_B(bufi, tile)                                         \
  { f16* _d = lds + 24576 + (bufi) * 8192 + wo;                   \
    const long _k = (long)(tile) << 6;                            \
    gld_lds16(Bg + _k, _d);                                       \
    gld_lds16(Bg + (long)32 * ldb + _k, _d + 2048);               \
    gld_lds16(Bg + (long)64 * ldb + _k, _d + 4096);               \
    gld_lds16(Bg + (long)96 * ldb + _k, _d + 6144); }

  const int nt = K >> 6;  // nt >= 2 guaranteed by callers
  // prologue: A(0),B(0) landed; A(1) left in flight
  STG_A(0, 0)
  STG_B(0, 0)
  STG_A(1, 1)
  asm volatile("s_waitcnt vmcnt(4)" ::: "memory");
  __builtin_amdgcn_s_barrier();
  asm volatile("" ::: "memory");

  for (int t = 0; t < nt; ++t) {
    if (t + 1 < nt) STG_B((t + 1) & 1, t + 1)
    if (t + 2 < nt) STG_A((t + 2) % 3, t + 2)
    const f16* Abuf = lds + (t % 3) * 8192;
    const f16* Bbuf = lds + 24576 + (t & 1) * 8192;
#pragma unroll
    for (int kk = 0; kk < 2; kk++) {
      f16x8 af[4], bfr[4];
      const int rchunk = (kk * 4 + (lane >> 4)) ^ (lane & 7);
#pragma unroll
      for (int mi = 0; mi < 4; mi++)
        af[mi] = *(const f16x8*)&Abuf[(wr * 64 + mi * 16 + (lane & 15)) * 64 + rchunk * 8];
#pragma unroll
      for (int ni = 0; ni < 4; ni++)
        bfr[ni] = *(const f16x8*)&Bbuf[(wc * 64 + ni * 16 + (lane & 15)) * 64 + rchunk * 8];
#pragma unroll
      for (int mi = 0; mi < 4; mi++)
#pragma unroll
        for (int ni = 0; ni < 4; ni++)
          acc[mi][ni] = __builtin_amdgcn_mfma_f32_16x16x32_f16(af[mi], bfr[ni], acc[mi][ni], 0, 0, 0);
    }
    if (t + 2 < nt) {
      asm volatile("s_waitcnt vmcnt(4)" ::: "memory");  // A(t+1),B(t+1) landed; A(t+2) in flight
    } else {
      asm volatile("s_waitcnt vmcnt(0)" ::: "memory");  // tail drain
    }
    __builtin_amdgcn_s_barrier();
    asm volatile("" ::: "memory");
  }
#undef STG_A
#undef STG_B

  const int r0 = (lane >> 4) * 4, cb = lane & 15;
#pragma unroll
  for (int ni = 0; ni < 4; ni++) {
    const int col = n0 + wc * 64 + ni * 16 + cb;
    const float bc = bias[col];
#pragma unroll
    for (int mi = 0; mi < 4; mi++) {
      const int row = m0 + wr * 64 + mi * 16 + r0;
#pragma unroll
      for (int r = 0; r < 4; r++)
        C[(long)(row + r) * ldc + col] = (f16)fast_tanh(acc[mi][ni][r] + bc);
    }
  }
}

// ---------------- gating head: logits = h1 @ gWa + gba; softmax over 4 -> gw [B,4] f32
__global__ __launch_bounds__(256) void k_gating_head(const f16* __restrict__ h1,
                                                     const float* __restrict__ gWa,
                                                     const float* __restrict__ gba,
                                                     float* __restrict__ gw, int B_) {
  const int b = blockIdx.x * 4 + (threadIdx.x >> 6);
  const int lane = threadIdx.x & 63;
  const f16x4 hv = *(const f16x4*)&h1[(long)b * 256 + lane * 4];
  float s0 = 0, s1 = 0, s2 = 0, s3 = 0;
#pragma unroll
  for (int j = 0; j < 4; j++) {
    const float hh = (float)hv[j];
    const float4 wr4 = *(const float4*)&gWa[(lane * 4 + j) * 4];
    s0 += hh * wr4.x; s1 += hh * wr4.y; s2 += hh * wr4.z; s3 += hh * wr4.w;
  }
#pragma unroll
  for (int off = 32; off >= 1; off >>= 1) {
    s0 += __shfl_xor(s0, off);
    s1 += __shfl_xor(s1, off);
    s2 += __shfl_xor(s2, off);
    s3 += __shfl_xor(s3, off);
  }
  const float l0 = s0 + gba[0], l1 = s1 + gba[1], l2 = s2 + gba[2], l3 = s3 + gba[3];
  float mx = fmaxf(fmaxf(l0, l1), fmaxf(l2, l3));
  const float e0 = __expf(l0 - mx), e1 = __expf(l1 - mx), e2 = __expf(l2 - mx), e3 = __expf(l3 - mx);
  const float inv = 1.0f / (e0 + e1 + e2 + e3);
  if (lane == 0) {
    float4 o; o.x = e0 * inv; o.y = e1 * inv; o.z = e2 * inv; o.w = e3 * inv;
    *(float4*)&gw[(long)b * 4] = o;
  }
}

// ---------------- fused head (g==4): out[b,a] = [sum_e gw[b,e]*((he1_e@Wt_e^T)[b,a]
//                  + eba[e,a])] * scale[a]; gw applied in-register per expert segment.
__global__ __launch_bounds__(256) void k_head2(const f16* __restrict__ he1,
                                               const f16* __restrict__ Wt,
                                               const float* __restrict__ eba,
                                               const float* __restrict__ scale,
                                               const float* __restrict__ gw,
                                               float* __restrict__ out,
                                               long sA) {
  constexpr int K = 512;
  __shared__ __align__(16) f16 As[2][64 * 64];
  __shared__ __align__(16) f16 Bs[2][64 * 64];
  const int tid = threadIdx.x, wave = tid >> 6, lane = tid & 63;
  const int bid = xcd_swizzle(blockIdx.x, gridDim.x);
  const long m0 = (long)bid * 64;
  const int swz = (tid & 7) ^ ((tid >> 3) & 7);
  const f16* Ag = he1 + (m0 + tid / 8) * K + swz * 8;
  const f16* Bg = Wt + (long)(tid / 8) * K + swz * 8;
  const int wo = wave * 512;
  const int r0 = (lane >> 4) * 4, cb = lane & 15;
  float4 gwv[4];
#pragma unroll
  for (int r = 0; r < 4; r++)
    gwv[r] = *(const float4*)&gw[(m0 + wave * 16 + r0 + r) * 4];
  f32x4 osum[4] = {};
  f32x4 acc[4] = {};

#pragma unroll
  for (int i = 0; i < 2; i++) {
    gld_lds16(Ag + (long)i * 32 * K, &As[0][wo + i * 2048]);
    gld_lds16(Bg + (long)i * 32 * K, &Bs[0][wo + i * 2048]);
  }
  __syncthreads();
  int cur = 0;
#pragma unroll
  for (int e = 0; e < 4; e++) {
    for (int kt = 0; kt < 8; ++kt) {
      const int s = e * 8 + kt;
      if (s + 1 < 32) {
        const int sn = s + 1;
        const long ae = (long)(sn >> 3) * sA + ((sn & 7) << 6);
        const long be = (long)(sn >> 3) * (64 * K) + ((sn & 7) << 6);
#pragma unroll
        for (int i = 0; i < 2; i++) {
          gld_lds16(Ag + ae + (long)i * 32 * K, &As[cur ^ 1][wo + i * 2048]);
          gld_lds16(Bg + be + (long)i * 32 * K, &Bs[cur ^ 1][wo + i * 2048]);
        }
      }
#pragma unroll
      for (int kk = 0; kk < 2; kk++) {
        const int rchunk = (kk * 4 + (lane >> 4)) ^ (lane & 7);
        const f16x8 a = *(const f16x8*)&As[cur][(wave * 16 + (lane & 15)) * 64 + rchunk * 8];
#pragma unroll
        for (int ni = 0; ni < 4; ni++) {
          const f16x8 bq = *(const f16x8*)&Bs[cur][(ni * 16 + (lane & 15)) * 64 + rchunk * 8];
          acc[ni] = __builtin_amdgcn_mfma_f32_16x16x32_f16(a, bq, acc[ni], 0, 0, 0);
        }
      }
      __syncthreads();
      cur ^= 1;
    }
#pragma unroll
    for (int ni = 0; ni < 4; ni++)
#pragma unroll
      for (int r = 0; r < 4; r++) {
        const float ge = (e == 0) ? gwv[r].x : (e == 1) ? gwv[r].y
                        : (e == 2) ? gwv[r].z : gwv[r].w;
        osum[ni][r] += ge * acc[ni][r];
        acc[ni][r] = 0.0f;
      }
  }

#pragma unroll
  for (int ni = 0; ni < 4; ni++) {
    const int col = ni * 16 + cb;
    const float sc = scale[col];
#pragma unroll
    for (int r = 0; r < 4; r++) {
      const long row = m0 + wave * 16 + r0 + r;
      const float b4 = gwv[r].x * eba[col] + gwv[r].y * eba[64 + col] +
                       gwv[r].z * eba[128 + col] + gwv[r].w * eba[192 + col];
      out[row * 64 + col] = (osum[ni][r] + b4) * sc;
    }
  }
}

// ---------------- per-expert head (fallback path)
__global__ __launch_bounds__(256) void k_head(const f16* __restrict__ he1,
                                              const f16* __restrict__ Wt,
                                              const float* __restrict__ ebae,
                                              const float* __restrict__ scale,
                                              const float* __restrict__ gw,
                                              float* __restrict__ outa,
                                              int e0, int K,
                                              long sA, long sB, long sBias, long sC) {
  const int z = blockIdx.z;
  he1 += (long)z * sA; Wt += (long)z * sB; ebae += (long)z * sBias; outa += (long)z * sC;
  const int e = e0 + z;
  __shared__ __align__(16) f16 As[2][64 * 64];
  __shared__ __align__(16) f16 Bs[2][64 * 64];
  const int tid = threadIdx.x, wave = tid >> 6, lane = tid & 63;
  const int bid = xcd_swizzle(blockIdx.x, gridDim.x);
  const long m0 = (long)bid * 64;
  f32x4 acc[4] = {};
  const int swz = (tid & 7) ^ ((tid >> 3) & 7);
  const f16* Ag = he1 + (m0 + tid / 8) * K + swz * 8;
  const f16* Bg = Wt + (long)(tid / 8) * K + swz * 8;
  const int wo = wave * 512;
#pragma unroll
  for (int i = 0; i < 2; i++) {
    gld_lds16(Ag + (long)i * 32 * K, &As[0][wo + i * 2048]);
    gld_lds16(Bg + (long)i * 32 * K, &Bs[0][wo + i * 2048]);
  }
  __syncthreads();
  const int nt = K >> 6;
  int cur = 0;
  for (int t = 0; t < nt; ++t) {
    if (t + 1 < nt) {
      const long kt = (long)(t + 1) << 6;
#pragma unroll
      for (int i = 0; i < 2; i++) {
        gld_lds16(Ag + (long)i * 32 * K + kt, &As[cur ^ 1][wo + i * 2048]);
        gld_lds16(Bg + (long)i * 32 * K + kt, &Bs[cur ^ 1][wo + i * 2048]);
      }
    }
#pragma unroll
    for (int kk = 0; kk < 2; kk++) {
      const int rchunk = (kk * 4 + (lane >> 4)) ^ (lane & 7);
      const f16x8 a = *(const f16x8*)&As[cur][(wave * 16 + (lane & 15)) * 64 + rchunk * 8];
#pragma unroll
      for (int ni = 0; ni < 4; ni++) {
        const f16x8 bq = *(const f16x8*)&Bs[cur][(ni * 16 + (lane & 15)) * 64 + rchunk * 8];
        acc[ni] = __builtin_amdgcn_mfma_f32_16x16x32_f16(a, bq, acc[ni], 0, 0, 0);
      }
    }
    __syncthreads();
    cur ^= 1;
  }
  const int r0 = (lane >> 4) * 4, cb = lane & 15;
#pragma unroll
  for (int ni = 0; ni < 4; ni++) {
    const int col = ni * 16 + cb;
    const float sb = scale[col], bb = ebae[col];
    const long row0 = m0 + wave * 16 + r0;
#pragma unroll
    for (int r = 0; r < 4; r++) {
      const long row = row0 + r;
      outa[row * 64 + col] = (acc[ni][r] + bb) * sb * gw[row * 4 + e];
    }
  }
}

// ---------------- combine: out = sum_e a_all[e] (fallback path)
__global__ __launch_bounds__(256) void k_combine(const float* __restrict__ a_all,
                                                 float* __restrict__ out, long n) {
  long i = ((long)blockIdx.x * 256 + threadIdx.x) * 4;
  if (i < n) {
    const float4 v0 = *(const float4*)(a_all + i);
    const float4 v1 = *(const float4*)(a_all + n + i);
    const float4 v2 = *(const float4*)(a_all + 2 * n + i);
    const float4 v3 = *(const float4*)(a_all + 3 * n + i);
    float4 o;
    o.x = v0.x + v1.x + v2.x + v3.x;
    o.y = v0.y + v1.y + v2.y + v3.y;
    o.z = v0.z + v1.z + v2.z + v3.z;
    o.w = v0.w + v1.w + v2.w + v3.w;
    *(float4*)(out + i) = o;
  }
}

// ---------------- launch ----------------
extern "C" void kernel_launch(void* const* d_in, const int* in_sizes, int n_in,
                              void* d_out, int out_size, void* d_ws, size_t ws_size,
                              hipStream_t stream) {
  constexpr int Bn = 16384, S = 512, H0G = 512, H1G = 256, H0E = 1024, H1E = 512, A = 64, E = 4;
  const float* x      = (const float*)d_in[0];
  const float* g_mean = (const float*)d_in[1];
  const float* g_std  = (const float*)d_in[2];
  const float* gW0    = (const float*)d_in[3];
  const float* gb0    = (const float*)d_in[4];
  const float* gW1    = (const float*)d_in[5];
  const float* gb1    = (const float*)d_in[6];
  const float* gWa    = (const float*)d_in[7];
  const float* gba    = (const float*)d_in[8];
  const float* e_mean = (const float*)d_in[9];
  const float* e_std  = (const float*)d_in[10];
  const float* eW0    = (const float*)d_in[11];
  const float* eb0    = (const float*)d_in[12];
  const float* eW1    = (const float*)d_in[13];
  const float* eb1    = (const float*)d_in[14];
  const float* eWa    = (const float*)d_in[15];
  const float* eba    = (const float*)d_in[16];
  const float* scale  = (const float*)d_in[17];
  float* out = (float*)d_out;

  char* p = (char*)d_ws;
  auto alloc = [&](size_t bytes) { char* q = p; p += (bytes + 255) & ~(size_t)255; return q; };
  f16* xh    = (f16*)alloc((size_t)Bn * S * 2);
  float* gw  = (float*)alloc((size_t)Bn * E * 4);
  float* a_all = (float*)alloc((size_t)E * Bn * A * 4);
  f16* gW0t  = (f16*)alloc((size_t)S * H0G * 2);
  f16* gW1t  = (f16*)alloc((size_t)H0G * H1G * 2);
  f16* eW0t  = (f16*)alloc((size_t)E * S * H0E * 2);
  f16* eW1t  = (f16*)alloc((size_t)E * H0E * H1E * 2);
  f16* eWat  = (f16*)alloc((size_t)E * H1E * A * 2);
  float* gb0c = (float*)alloc((size_t)H0G * 4);
  float* eb0c = (float*)alloc((size_t)E * H0E * 4);
  f16* h0g   = (f16*)alloc((size_t)Bn * H0G * 2);
  const size_t base = (size_t)(p - (char*)d_ws);
  const size_t per_g = ((size_t)Bn * H0E * 2 + 256) + ((size_t)Bn * H1E * 2 + 256);
  int g = 1;
  if (ws_size >= base + 4 * per_g) g = 4;
  else if (ws_size >= base + 2 * per_g) g = 2;
  f16* he0_g = (f16*)alloc((size_t)g * Bn * H0E * 2);  // [g][Bn][1024]
  f16* he1_g = (f16*)alloc((size_t)g * Bn * H1E * 2);  // [g][Bn][512]
  f16* h1g = he1_g;  // gating h1 aliases he1 scratch (read before expert L1 writes)

  // prep
  k_cvt_x<<<2048, 256, 0, stream>>>(x, xh, (long)Bn * S);
  k_transpose<<<dim3(H0G / 32, S / 32, 1), dim3(32, 8), 0, stream>>>(gW0, gW0t, g_std, S, H0G);
  k_transpose<<<dim3(H1G / 32, H0G / 32, 1), dim3(32, 8), 0, stream>>>(gW1, gW1t, nullptr, H0G, H1G);
  k_transpose<<<dim3(H0E / 32, S / 32, E), dim3(32, 8), 0, stream>>>(eW0, eW0t, e_std, S, H0E);
  k_transpose<<<dim3(H1E / 32, H0E / 32, E), dim3(32, 8), 0, stream>>>(eW1, eW1t, nullptr, H0E, H1E);
  k_transpose<<<dim3(A / 32, H1E / 32, E), dim3(32, 8), 0, stream>>>(eWa, eWat, nullptr, H1E, A);
  k_bias_corr<<<dim3(H0G / 64, 1), dim3(64, 16), 0, stream>>>(gW0, gb0, g_mean, g_std, gb0c, S, H0G);
  k_bias_corr<<<dim3(H0E / 64, E), dim3(64, 16), 0, stream>>>(eW0, eb0, e_mean, e_std, eb0c, S, H0E);

  constexpr size_t LDSCV = 5 * 128 * 64 * sizeof(f16);  // 80 KiB (A x3 + B x2)

  // gating trunk + softmax head
  k_gemm_cv<<<dim3(H0G / 128, Bn / 128, 1), 256, LDSCV, stream>>>(
      xh, gW0t, gb0c, h0g, Bn, S, S, S, H0G, 0, 0, 0, 0);
  k_gemm_cv<<<dim3(H1G / 128, Bn / 128, 1), 256, LDSCV, stream>>>(
      h0g, gW1t, gb1, h1g, Bn, H0G, H0G, H0G, H1G, 0, 0, 0, 0);
  k_gating_head<<<Bn / 4, 256, 0, stream>>>(h1g, gWa, gba, gw, Bn);

  if (g == 4) {
    // expert L0: z=4, shared A (xh)
    k_gemm_cv<<<dim3(H0E / 128, Bn / 128, 4), 256, LDSCV, stream>>>(
        xh, eW0t, eb0c, he0_g, Bn, S, S, S, H0E,
        0, (long)S * H0E, H0E, (long)Bn * H0E);
    // expert L1: z=4 (unscaled; gw applied in k_head2)
    k_gemm_cv<<<dim3(H1E / 128, Bn / 128, 4), 256, LDSCV, stream>>>(
        he0_g, eW1t, eb1, he1_g, Bn, H0E, H0E, H0E, H1E,
        (long)Bn * H0E, (long)H0E * H1E, H1E, (long)Bn * H1E);
    // fused head over concat-K (4 x 512), writes out directly
    k_head2<<<dim3(Bn / 64), 256, 0, stream>>>(
        he1_g, eWat, eba, scale, gw, out, (long)Bn * H1E);
  } else {
    for (int e0 = 0; e0 < E; e0 += g) {
      k_gemm_cv<<<dim3(H0E / 128, Bn / 128, g), 256, LDSCV, stream>>>(
          xh, eW0t + (size_t)e0 * S * H0E, eb0c + (size_t)e0 * H0E, he0_g,
          Bn, S, S, S, H0E,
          0, (long)S * H0E, H0E, (long)Bn * H0E);
      k_gemm_cv<<<dim3(H1E / 128, Bn / 128, g), 256, LDSCV, stream>>>(
          he0_g, eW1t + (size_t)e0 * H0E * H1E, eb1 + (size_t)e0 * H1E, he1_g,
          Bn, H0E, H0E, H0E, H1E,
          (long)Bn * H0E, (long)H0E * H1E, H1E, (long)Bn * H1E);
      k_head<<<dim3(Bn / 64, 1, g), 256, 0, stream>>>(
          he1_g, eWat + (size_t)e0 * H1E * A, eba + (size_t)e0 * A, scale, gw,
          a_all + (size_t)e0 * Bn * A, e0, H1E,
          (long)Bn * H1E, (long)H1E * A, A, (long)Bn * A);
    }
    k_combine<<<(Bn * A) / 1024, 256, 0, stream>>>(a_all, out, (long)Bn * A);
  }
}

// Round 12
// 293.436 us; speedup vs baseline: 1.3053x; 1.0110x over previous
//
#include <hip/hip_runtime.h>
#include <hip/hip_bf16.h>

typedef _Float16 f16;
typedef _Float16 f16x4 __attribute__((ext_vector_type(4)));
typedef _Float16 f16x8 __attribute__((ext_vector_type(8)));
typedef float f32x4 __attribute__((ext_vector_type(4)));

#define DEV static __device__ __forceinline__

DEV void gld_lds16(const void* g, void* l) {
  __builtin_amdgcn_global_load_lds(
      (const __attribute__((address_space(1))) void*)g,
      (__attribute__((address_space(3))) void*)l, 16, 0, 0);
}

DEV float fast_tanh(float x) {
  float e = __expf(2.0f * x);
  return 1.0f - 2.0f / (e + 1.0f);
}

DEV int xcd_swizzle(int raw, int nwg) {
  return ((nwg & 7) == 0) ? ((raw & 7) * (nwg >> 3) + (raw >> 3)) : raw;
}

// ---------------- x (f32) -> xh (f16) ----------------
__global__ __launch_bounds__(256) void k_cvt_x(const float* __restrict__ x,
                                               f16* __restrict__ xh, long n) {
  long i0 = ((long)blockIdx.x * 256 + threadIdx.x) * 4;
  long stride = (long)gridDim.x * 1024;
  for (long i = i0; i < n; i += stride) {
    const float4 v = *(const float4*)(x + i);
    f16x4 h;
    h.x = (f16)v.x; h.y = (f16)v.y; h.z = (f16)v.z; h.w = (f16)v.w;
    *(f16x4*)(xh + i) = h;
  }
}

// ---------------- W [E][K][N] f32 -> Wt [E][N][K] f16, optional col-scale 1/std[k]
__global__ __launch_bounds__(256) void k_transpose(const float* __restrict__ in,
                                                   f16* __restrict__ out,
                                                   const float* __restrict__ stdv,
                                                   int K_, int N_) {
  __shared__ float tile[32][33];
  const int e = blockIdx.z;
  const float* ine = in + (long)e * K_ * N_;
  f16* oute = out + (long)e * K_ * N_;
  const int n0 = blockIdx.x * 32, k0 = blockIdx.y * 32;
  const int tx = threadIdx.x, ty = threadIdx.y;
#pragma unroll
  for (int j = 0; j < 4; j++)
    tile[ty + j * 8][tx] = ine[(long)(k0 + ty + j * 8) * N_ + n0 + tx];
  __syncthreads();
  const float rs = stdv ? 1.0f / stdv[(long)e * K_ + k0 + tx] : 1.0f;
#pragma unroll
  for (int j = 0; j < 4; j++)
    oute[(long)(n0 + ty + j * 8) * K_ + k0 + tx] = (f16)(tile[tx][ty + j * 8] * rs);
}

// ---------------- corrected bias: outb[e][h] = b[e][h] - sum_s (mean/std)[e][s]*W[e][s][h]
__global__ __launch_bounds__(1024) void k_bias_corr(const float* __restrict__ W,
                                                    const float* __restrict__ b,
                                                    const float* __restrict__ mean,
                                                    const float* __restrict__ stdv,
                                                    float* __restrict__ outb,
                                                    int S_, int H_) {
  __shared__ float red[16][64];
  const int e = blockIdx.y;
  const float* We = W + (long)e * S_ * H_;
  const float* me = mean + (long)e * S_;
  const float* se = stdv + (long)e * S_;
  const int h = blockIdx.x * 64 + threadIdx.x;
  const int sl = threadIdx.y;
  float acc = 0.0f;
#pragma unroll 4
  for (int s = sl; s < S_; s += 16) acc += (me[s] / se[s]) * We[(long)s * H_ + h];
  red[sl][threadIdx.x] = acc;
  __syncthreads();
  if (sl == 0) {
    float a = 0.0f;
#pragma unroll
    for (int j = 0; j < 16; j++) a += red[j][threadIdx.x];
    outb[(long)e * H_ + h] = b[(long)e * H_ + h] - a;
  }
}

// ---------------- 128x128 GEMM, BK=64, counted-vmcnt pipeline (R11, proven).
__global__ __launch_bounds__(256) void k_gemm_cv(
    const f16* __restrict__ A, const f16* __restrict__ Bt,
    const float* __restrict__ bias, f16* __restrict__ C,
    int M, int K, int lda, int ldb, int ldc,
    long sA, long sB, long sBias, long sC) {
  A += (long)blockIdx.z * sA; Bt += (long)blockIdx.z * sB;
  bias += (long)blockIdx.z * sBias; C += (long)blockIdx.z * sC;
  extern __shared__ __align__(16) f16 lds[];  // A: 3*8192 f16, B at 24576 + 2*8192
  const int tid = threadIdx.x, wave = tid >> 6, lane = tid & 63;
  const int nwg = gridDim.x * gridDim.y;
  const int logical = xcd_swizzle(blockIdx.y * gridDim.x + blockIdx.x, nwg);
  const int bx = logical % gridDim.x, by = logical / gridDim.x;
  const int m0 = by * 128, n0 = bx * 128;
  const int wr = wave >> 1, wc = wave & 1;
  f32x4 acc[4][4] = {};
  const int swz = (tid & 7) ^ ((tid >> 3) & 7);
  const f16* Ag = A + (long)(m0 + (tid >> 3)) * lda + swz * 8;
  const f16* Bg = Bt + (long)(n0 + (tid >> 3)) * ldb + swz * 8;
  const int wo = wave * 512;

#define STG_A(bufi, tile)                                         \
  { f16* _d = lds + (bufi) * 8192 + wo;                           \
    const long _k = (long)(tile) << 6;                            \
    gld_lds16(Ag + _k, _d);                                       \
    gld_lds16(Ag + (long)32 * lda + _k, _d + 2048);               \
    gld_lds16(Ag + (long)64 * lda + _k, _d + 4096);               \
    gld_lds16(Ag + (long)96 * lda + _k, _d + 6144); }
#define STG_B(bufi, tile)                                         \
  { f16* _d = lds + 24576 + (bufi) * 8192 + wo;                   \
    const long _k = (long)(tile) << 6;                            \
    gld_lds16(Bg + _k, _d);                                       \
    gld_lds16(Bg + (long)32 * ldb + _k, _d + 2048);               \
    gld_lds16(Bg + (long)64 * ldb + _k, _d + 4096);               \
    gld_lds16(Bg + (long)96 * ldb + _k, _d + 6144); }

  const int nt = K >> 6;  // nt >= 2
  STG_A(0, 0)
  STG_B(0, 0)
  STG_A(1, 1)
  asm volatile("s_waitcnt vmcnt(4)" ::: "memory");
  __builtin_amdgcn_s_barrier();
  asm volatile("" ::: "memory");

  for (int t = 0; t < nt; ++t) {
    if (t + 1 < nt) STG_B((t + 1) & 1, t + 1)
    if (t + 2 < nt) STG_A((t + 2) % 3, t + 2)
    const f16* Abuf = lds + (t % 3) * 8192;
    const f16* Bbuf = lds + 24576 + (t & 1) * 8192;
#pragma unroll
    for (int kk = 0; kk < 2; kk++) {
      f16x8 af[4], bfr[4];
      const int rchunk = (kk * 4 + (lane >> 4)) ^ (lane & 7);
#pragma unroll
      for (int mi = 0; mi < 4; mi++)
        af[mi] = *(const f16x8*)&Abuf[(wr * 64 + mi * 16 + (lane & 15)) * 64 + rchunk * 8];
#pragma unroll
      for (int ni = 0; ni < 4; ni++)
        bfr[ni] = *(const f16x8*)&Bbuf[(wc * 64 + ni * 16 + (lane & 15)) * 64 + rchunk * 8];
#pragma unroll
      for (int mi = 0; mi < 4; mi++)
#pragma unroll
        for (int ni = 0; ni < 4; ni++)
          acc[mi][ni] = __builtin_amdgcn_mfma_f32_16x16x32_f16(af[mi], bfr[ni], acc[mi][ni], 0, 0, 0);
    }
    if (t + 2 < nt) {
      asm volatile("s_waitcnt vmcnt(4)" ::: "memory");
    } else {
      asm volatile("s_waitcnt vmcnt(0)" ::: "memory");
    }
    __builtin_amdgcn_s_barrier();
    asm volatile("" ::: "memory");
  }
#undef STG_A
#undef STG_B

  const int r0 = (lane >> 4) * 4, cb = lane & 15;
#pragma unroll
  for (int ni = 0; ni < 4; ni++) {
    const int col = n0 + wc * 64 + ni * 16 + cb;
    const float bc = bias[col];
#pragma unroll
    for (int mi = 0; mi < 4; mi++) {
      const int row = m0 + wr * 64 + mi * 16 + r0;
#pragma unroll
      for (int r = 0; r < 4; r++)
        C[(long)(row + r) * ldc + col] = (f16)fast_tanh(acc[mi][ni][r] + bc);
    }
  }
}

// ---------------- 256x256 8-phase GEMM (experts). 512 thr = 8 waves (2M x 4N),
// wave tile 128x64, BK=64, 2-buffer 128 KiB LDS. 4 phases per K-tile j:
//   q0: read af(kk0)+bfr01(kk0) | stage A1[j+1]   -> MFMA ni01
//   q1: read bfr23(kk0)         | stage B0[j+1]   -> MFMA ni23
//   q2: read af(kk1)+bfr01(kk1) | stage B1[j+1]   -> MFMA ni01
//   q3: read bfr23(kk1)         | stage A0[j+2]   -> MFMA ni23; vmcnt(2|0)
// Invariants (verified): stage targets sealed >=1 barrier before issue;
// vmcnt(2) at q3 forces K-tile j+1 fully landed (only A0[j+2] in flight).
// Swizzle = R4 chunk-XOR (2-way, free). C = tanh(A@Bt^T + bias). K%64==0, nt>=2.
__global__ __launch_bounds__(512, 2) void k_gemm_8p(
    const f16* __restrict__ A, const f16* __restrict__ Bt,
    const float* __restrict__ bias, f16* __restrict__ C,
    int M, int K, int lda, int ldb, int ldc,
    long sA, long sB, long sBias, long sC) {
  A += (long)blockIdx.z * sA; Bt += (long)blockIdx.z * sB;
  bias += (long)blockIdx.z * sBias; C += (long)blockIdx.z * sC;
  extern __shared__ __align__(16) f16 lds[];  // buf b: A at b*32768 (256x64), B at +16384
  const int tid = threadIdx.x, wave = tid >> 6, lane = tid & 63;
  const int nwg = gridDim.x * gridDim.y;
  const int logical = xcd_swizzle(blockIdx.y * gridDim.x + blockIdx.x, nwg);
  const int bx = logical % gridDim.x, by = logical / gridDim.x;
  const int m0 = by * 256, n0 = bx * 256;
  const int wr = wave >> 2, wc = wave & 3;
  f32x4 acc[8][4] = {};

  const int swz = (tid & 7) ^ ((tid >> 3) & 7);
  const f16* Ag = A + (long)(m0 + (tid >> 3)) * lda + swz * 8;
  const f16* Bg = Bt + (long)(n0 + (tid >> 3)) * ldb + swz * 8;
  const int tdst = tid * 8;  // f16 units within an 8KB call slab

  const int rc0 = (lane >> 4) ^ (lane & 7);        // kk0 physical chunk
  const int rc1 = (4 + (lane >> 4)) ^ (lane & 7);  // kk1
  int aoff[8], boff[4];
#pragma unroll
  for (int mi = 0; mi < 8; mi++) aoff[mi] = (wr * 128 + mi * 16 + (lane & 15)) * 64;
#pragma unroll
  for (int ni = 0; ni < 4; ni++) boff[ni] = 16384 + (wc * 64 + ni * 16 + (lane & 15)) * 64;

// stage half h (0/1 = rows h*128..h*128+127) of K-tile jt: 2 calls of 64 rows
#define STG_A(jt, h)                                                          \
  { f16* _d = lds + ((jt) & 1) * 32768 + (h) * 8192 + tdst;                   \
    const long _k = (long)(jt) << 6;                                          \
    gld_lds16(Ag + (long)((h) * 128) * lda + _k, _d);                         \
    gld_lds16(Ag + (long)((h) * 128 + 64) * lda + _k, _d + 4096); }
#define STG_B(jt, h)                                                          \
  { f16* _d = lds + ((jt) & 1) * 32768 + 16384 + (h) * 8192 + tdst;           \
    const long _k = (long)(jt) << 6;                                          \
    gld_lds16(Bg + (long)((h) * 128) * ldb + _k, _d);                         \
    gld_lds16(Bg + (long)((h) * 128 + 64) * ldb + _k, _d + 4096); }
#define LOAD_A(b, rc)                                                         \
  _Pragma("unroll") for (int mi = 0; mi < 8; mi++)                            \
      af[mi] = *(const f16x8*)&lds[(b) * 32768 + aoff[mi] + (rc) * 8];
#define LOAD_B(b, ni, rc)                                                     \
  bfr[ni] = *(const f16x8*)&lds[(b) * 32768 + boff[ni] + (rc) * 8];
#define MMA2(nA, nB)                                                          \
  __builtin_amdgcn_s_setprio(1);                                              \
  _Pragma("unroll") for (int mi = 0; mi < 8; mi++) {                          \
    acc[mi][nA] = __builtin_amdgcn_mfma_f32_16x16x32_f16(af[mi], bfr[nA], acc[mi][nA], 0, 0, 0); \
    acc[mi][nB] = __builtin_amdgcn_mfma_f32_16x16x32_f16(af[mi], bfr[nB], acc[mi][nB], 0, 0, 0); \
  }                                                                           \
  __builtin_amdgcn_s_setprio(0);
#define BAR()                                                                 \
  __builtin_amdgcn_s_barrier();                                               \
  asm volatile("" ::: "memory")
#define WAITL()                                                               \
  asm volatile("s_waitcnt lgkmcnt(0)" ::: "memory");                          \
  __builtin_amdgcn_sched_barrier(0)

  const int nt = K >> 6;  // nt >= 2

  // prologue: K-tile 0 (4 half-tiles) + A0 of K-tile 1; allow A0[1] in flight
  STG_A(0, 0) STG_A(0, 1) STG_B(0, 0) STG_B(0, 1)
  STG_A(1, 0)
  asm volatile("s_waitcnt vmcnt(2)" ::: "memory");
  BAR();

  f16x8 af[8], bfr[4];
  for (int j = 0; j < nt; ++j) {
    const int b = j & 1;
    // q0
    LOAD_A(b, rc0) LOAD_B(b, 0, rc0) LOAD_B(b, 1, rc0)
    if (j + 1 < nt) STG_A(j + 1, 1)
    BAR(); WAITL(); MMA2(0, 1) BAR();
    // q1
    LOAD_B(b, 2, rc0) LOAD_B(b, 3, rc0)
    if (j + 1 < nt) STG_B(j + 1, 0)
    BAR(); WAITL(); MMA2(2, 3) BAR();
    // q2
    LOAD_A(b, rc1) LOAD_B(b, 0, rc1) LOAD_B(b, 1, rc1)
    if (j + 1 < nt) STG_B(j + 1, 1)
    BAR(); WAITL(); MMA2(0, 1) BAR();
    // q3
    LOAD_B(b, 2, rc1) LOAD_B(b, 3, rc1)
    if (j + 2 < nt) STG_A(j + 2, 0)
    BAR(); WAITL(); MMA2(2, 3)
    if (j + 1 < nt) {
      if (j + 2 < nt) {
        asm volatile("s_waitcnt vmcnt(2)" ::: "memory");  // K-tile j+1 landed; A0[j+2] in flight
      } else {
        asm volatile("s_waitcnt vmcnt(0)" ::: "memory");  // tail: nothing younger
      }
    }
    BAR();
  }
#undef STG_A
#undef STG_B
#undef LOAD_A
#undef LOAD_B
#undef MMA2
#undef BAR
#undef WAITL

  const int r0 = (lane >> 4) * 4, cb = lane & 15;
  float bcv[4];
#pragma unroll
  for (int ni = 0; ni < 4; ni++) bcv[ni] = bias[n0 + wc * 64 + ni * 16 + cb];
#pragma unroll
  for (int mi = 0; mi < 8; mi++) {
#pragma unroll
    for (int r = 0; r < 4; r++) {
      const long row = m0 + wr * 128 + mi * 16 + r0 + r;
#pragma unroll
      for (int ni = 0; ni < 4; ni++) {
        const int col = n0 + wc * 64 + ni * 16 + cb;
        C[row * (long)ldc + col] = (f16)fast_tanh(acc[mi][ni][r] + bcv[ni]);
      }
    }
  }
}

// ---------------- gating head: logits = h1 @ gWa + gba; softmax over 4 -> gw [B,4] f32
__global__ __launch_bounds__(256) void k_gating_head(const f16* __restrict__ h1,
                                                     const float* __restrict__ gWa,
                                                     const float* __restrict__ gba,
                                                     float* __restrict__ gw, int B_) {
  const int b = blockIdx.x * 4 + (threadIdx.x >> 6);
  const int lane = threadIdx.x & 63;
  const f16x4 hv = *(const f16x4*)&h1[(long)b * 256 + lane * 4];
  float s0 = 0, s1 = 0, s2 = 0, s3 = 0;
#pragma unroll
  for (int j = 0; j < 4; j++) {
    const float hh = (float)hv[j];
    const float4 wr4 = *(const float4*)&gWa[(lane * 4 + j) * 4];
    s0 += hh * wr4.x; s1 += hh * wr4.y; s2 += hh * wr4.z; s3 += hh * wr4.w;
  }
#pragma unroll
  for (int off = 32; off >= 1; off >>= 1) {
    s0 += __shfl_xor(s0, off);
    s1 += __shfl_xor(s1, off);
    s2 += __shfl_xor(s2, off);
    s3 += __shfl_xor(s3, off);
  }
  const float l0 = s0 + gba[0], l1 = s1 + gba[1], l2 = s2 + gba[2], l3 = s3 + gba[3];
  float mx = fmaxf(fmaxf(l0, l1), fmaxf(l2, l3));
  const float e0 = __expf(l0 - mx), e1 = __expf(l1 - mx), e2 = __expf(l2 - mx), e3 = __expf(l3 - mx);
  const float inv = 1.0f / (e0 + e1 + e2 + e3);
  if (lane == 0) {
    float4 o; o.x = e0 * inv; o.y = e1 * inv; o.z = e2 * inv; o.w = e3 * inv;
    *(float4*)&gw[(long)b * 4] = o;
  }
}

// ---------------- fused head (g==4): out[b,a] = [sum_e gw[b,e]*((he1_e@Wt_e^T)[b,a]
//                  + eba[e,a])] * scale[a]; gw applied in-register per expert segment.
__global__ __launch_bounds__(256) void k_head2(const f16* __restrict__ he1,
                                               const f16* __restrict__ Wt,
                                               const float* __restrict__ eba,
                                               const float* __restrict__ scale,
                                               const float* __restrict__ gw,
                                               float* __restrict__ out,
                                               long sA) {
  constexpr int K = 512;
  __shared__ __align__(16) f16 As[2][64 * 64];
  __shared__ __align__(16) f16 Bs[2][64 * 64];
  const int tid = threadIdx.x, wave = tid >> 6, lane = tid & 63;
  const int bid = xcd_swizzle(blockIdx.x, gridDim.x);
  const long m0 = (long)bid * 64;
  const int swz = (tid & 7) ^ ((tid >> 3) & 7);
  const f16* Ag = he1 + (m0 + tid / 8) * K + swz * 8;
  const f16* Bg = Wt + (long)(tid / 8) * K + swz * 8;
  const int wo = wave * 512;
  const int r0 = (lane >> 4) * 4, cb = lane & 15;
  float4 gwv[4];
#pragma unroll
  for (int r = 0; r < 4; r++)
    gwv[r] = *(const float4*)&gw[(m0 + wave * 16 + r0 + r) * 4];
  f32x4 osum[4] = {};
  f32x4 acc[4] = {};

#pragma unroll
  for (int i = 0; i < 2; i++) {
    gld_lds16(Ag + (long)i * 32 * K, &As[0][wo + i * 2048]);
    gld_lds16(Bg + (long)i * 32 * K, &Bs[0][wo + i * 2048]);
  }
  __syncthreads();
  int cur = 0;
#pragma unroll
  for (int e = 0; e < 4; e++) {
    for (int kt = 0; kt < 8; ++kt) {
      const int s = e * 8 + kt;
      if (s + 1 < 32) {
        const int sn = s + 1;
        const long ae = (long)(sn >> 3) * sA + ((sn & 7) << 6);
        const long be = (long)(sn >> 3) * (64 * K) + ((sn & 7) << 6);
#pragma unroll
        for (int i = 0; i < 2; i++) {
          gld_lds16(Ag + ae + (long)i * 32 * K, &As[cur ^ 1][wo + i * 2048]);
          gld_lds16(Bg + be + (long)i * 32 * K, &Bs[cur ^ 1][wo + i * 2048]);
        }
      }
#pragma unroll
      for (int kk = 0; kk < 2; kk++) {
        const int rchunk = (kk * 4 + (lane >> 4)) ^ (lane & 7);
        const f16x8 a = *(const f16x8*)&As[cur][(wave * 16 + (lane & 15)) * 64 + rchunk * 8];
#pragma unroll
        for (int ni = 0; ni < 4; ni++) {
          const f16x8 bq = *(const f16x8*)&Bs[cur][(ni * 16 + (lane & 15)) * 64 + rchunk * 8];
          acc[ni] = __builtin_amdgcn_mfma_f32_16x16x32_f16(a, bq, acc[ni], 0, 0, 0);
        }
      }
      __syncthreads();
      cur ^= 1;
    }
#pragma unroll
    for (int ni = 0; ni < 4; ni++)
#pragma unroll
      for (int r = 0; r < 4; r++) {
        const float ge = (e == 0) ? gwv[r].x : (e == 1) ? gwv[r].y
                        : (e == 2) ? gwv[r].z : gwv[r].w;
        osum[ni][r] += ge * acc[ni][r];
        acc[ni][r] = 0.0f;
      }
  }

#pragma unroll
  for (int ni = 0; ni < 4; ni++) {
    const int col = ni * 16 + cb;
    const float sc = scale[col];
#pragma unroll
    for (int r = 0; r < 4; r++) {
      const long row = m0 + wave * 16 + r0 + r;
      const float b4 = gwv[r].x * eba[col] + gwv[r].y * eba[64 + col] +
                       gwv[r].z * eba[128 + col] + gwv[r].w * eba[192 + col];
      out[row * 64 + col] = (osum[ni][r] + b4) * sc;
    }
  }
}

// ---------------- per-expert head (fallback path)
__global__ __launch_bounds__(256) void k_head(const f16* __restrict__ he1,
                                              const f16* __restrict__ Wt,
                                              const float* __restrict__ ebae,
                                              const float* __restrict__ scale,
                                              const float* __restrict__ gw,
                                              float* __restrict__ outa,
                                              int e0, int K,
                                              long sA, long sB, long sBias, long sC) {
  const int z = blockIdx.z;
  he1 += (long)z * sA; Wt += (long)z * sB; ebae += (long)z * sBias; outa += (long)z * sC;
  const int e = e0 + z;
  __shared__ __align__(16) f16 As[2][64 * 64];
  __shared__ __align__(16) f16 Bs[2][64 * 64];
  const int tid = threadIdx.x, wave = tid >> 6, lane = tid & 63;
  const int bid = xcd_swizzle(blockIdx.x, gridDim.x);
  const long m0 = (long)bid * 64;
  f32x4 acc[4] = {};
  const int swz = (tid & 7) ^ ((tid >> 3) & 7);
  const f16* Ag = he1 + (m0 + tid / 8) * K + swz * 8;
  const f16* Bg = Wt + (long)(tid / 8) * K + swz * 8;
  const int wo = wave * 512;
#pragma unroll
  for (int i = 0; i < 2; i++) {
    gld_lds16(Ag + (long)i * 32 * K, &As[0][wo + i * 2048]);
    gld_lds16(Bg + (long)i * 32 * K, &Bs[0][wo + i * 2048]);
  }
  __syncthreads();
  const int nt = K >> 6;
  int cur = 0;
  for (int t = 0; t < nt; ++t) {
    if (t + 1 < nt) {
      const long kt = (long)(t + 1) << 6;
#pragma unroll
      for (int i = 0; i < 2; i++) {
        gld_lds16(Ag + (long)i * 32 * K + kt, &As[cur ^ 1][wo + i * 2048]);
        gld_lds16(Bg + (long)i * 32 * K + kt, &Bs[cur ^ 1][wo + i * 2048]);
      }
    }
#pragma unroll
    for (int kk = 0; kk < 2; kk++) {
      const int rchunk = (kk * 4 + (lane >> 4)) ^ (lane & 7);
      const f16x8 a = *(const f16x8*)&As[cur][(wave * 16 + (lane & 15)) * 64 + rchunk * 8];
#pragma unroll
      for (int ni = 0; ni < 4; ni++) {
        const f16x8 bq = *(const f16x8*)&Bs[cur][(ni * 16 + (lane & 15)) * 64 + rchunk * 8];
        acc[ni] = __builtin_amdgcn_mfma_f32_16x16x32_f16(a, bq, acc[ni], 0, 0, 0);
      }
    }
    __syncthreads();
    cur ^= 1;
  }
  const int r0 = (lane >> 4) * 4, cb = lane & 15;
#pragma unroll
  for (int ni = 0; ni < 4; ni++) {
    const int col = ni * 16 + cb;
    const float sb = scale[col], bb = ebae[col];
    const long row0 = m0 + wave * 16 + r0;
#pragma unroll
    for (int r = 0; r < 4; r++) {
      const long row = row0 + r;
      outa[row * 64 + col] = (acc[ni][r] + bb) * sb * gw[row * 4 + e];
    }
  }
}

// ---------------- combine: out = sum_e a_all[e] (fallback path)
__global__ __launch_bounds__(256) void k_combine(const float* __restrict__ a_all,
                                                 float* __restrict__ out, long n) {
  long i = ((long)blockIdx.x * 256 + threadIdx.x) * 4;
  if (i < n) {
    const float4 v0 = *(const float4*)(a_all + i);
    const float4 v1 = *(const float4*)(a_all + n + i);
    const float4 v2 = *(const float4*)(a_all + 2 * n + i);
    const float4 v3 = *(const float4*)(a_all + 3 * n + i);
    float4 o;
    o.x = v0.x + v1.x + v2.x + v3.x;
    o.y = v0.y + v1.y + v2.y + v3.y;
    o.z = v0.z + v1.z + v2.z + v3.z;
    o.w = v0.w + v1.w + v2.w + v3.w;
    *(float4*)(out + i) = o;
  }
}

// ---------------- launch ----------------
extern "C" void kernel_launch(void* const* d_in, const int* in_sizes, int n_in,
                              void* d_out, int out_size, void* d_ws, size_t ws_size,
                              hipStream_t stream) {
  constexpr int Bn = 16384, S = 512, H0G = 512, H1G = 256, H0E = 1024, H1E = 512, A = 64, E = 4;
  const float* x      = (const float*)d_in[0];
  const float* g_mean = (const float*)d_in[1];
  const float* g_std  = (const float*)d_in[2];
  const float* gW0    = (const float*)d_in[3];
  const float* gb0    = (const float*)d_in[4];
  const float* gW1    = (const float*)d_in[5];
  const float* gb1    = (const float*)d_in[6];
  const float* gWa    = (const float*)d_in[7];
  const float* gba    = (const float*)d_in[8];
  const float* e_mean = (const float*)d_in[9];
  const float* e_std  = (const float*)d_in[10];
  const float* eW0    = (const float*)d_in[11];
  const float* eb0    = (const float*)d_in[12];
  const float* eW1    = (const float*)d_in[13];
  const float* eb1    = (const float*)d_in[14];
  const float* eWa    = (const float*)d_in[15];
  const float* eba    = (const float*)d_in[16];
  const float* scale  = (const float*)d_in[17];
  float* out = (float*)d_out;

  char* p = (char*)d_ws;
  auto alloc = [&](size_t bytes) { char* q = p; p += (bytes + 255) & ~(size_t)255; return q; };
  f16* xh    = (f16*)alloc((size_t)Bn * S * 2);
  float* gw  = (float*)alloc((size_t)Bn * E * 4);
  float* a_all = (float*)alloc((size_t)E * Bn * A * 4);
  f16* gW0t  = (f16*)alloc((size_t)S * H0G * 2);
  f16* gW1t  = (f16*)alloc((size_t)H0G * H1G * 2);
  f16* eW0t  = (f16*)alloc((size_t)E * S * H0E * 2);
  f16* eW1t  = (f16*)alloc((size_t)E * H0E * H1E * 2);
  f16* eWat  = (f16*)alloc((size_t)E * H1E * A * 2);
  float* gb0c = (float*)alloc((size_t)H0G * 4);
  float* eb0c = (float*)alloc((size_t)E * H0E * 4);
  f16* h0g   = (f16*)alloc((size_t)Bn * H0G * 2);
  const size_t base = (size_t)(p - (char*)d_ws);
  const size_t per_g = ((size_t)Bn * H0E * 2 + 256) + ((size_t)Bn * H1E * 2 + 256);
  int g = 1;
  if (ws_size >= base + 4 * per_g) g = 4;
  else if (ws_size >= base + 2 * per_g) g = 2;
  f16* he0_g = (f16*)alloc((size_t)g * Bn * H0E * 2);  // [g][Bn][1024]
  f16* he1_g = (f16*)alloc((size_t)g * Bn * H1E * 2);  // [g][Bn][512]
  f16* h1g = he1_g;  // gating h1 aliases he1 scratch (read before expert L1 writes)

  // prep
  k_cvt_x<<<2048, 256, 0, stream>>>(x, xh, (long)Bn * S);
  k_transpose<<<dim3(H0G / 32, S / 32, 1), dim3(32, 8), 0, stream>>>(gW0, gW0t, g_std, S, H0G);
  k_transpose<<<dim3(H1G / 32, H0G / 32, 1), dim3(32, 8), 0, stream>>>(gW1, gW1t, nullptr, H0G, H1G);
  k_transpose<<<dim3(H0E / 32, S / 32, E), dim3(32, 8), 0, stream>>>(eW0, eW0t, e_std, S, H0E);
  k_transpose<<<dim3(H1E / 32, H0E / 32, E), dim3(32, 8), 0, stream>>>(eW1, eW1t, nullptr, H0E, H1E);
  k_transpose<<<dim3(A / 32, H1E / 32, E), dim3(32, 8), 0, stream>>>(eWa, eWat, nullptr, H1E, A);
  k_bias_corr<<<dim3(H0G / 64, 1), dim3(64, 16), 0, stream>>>(gW0, gb0, g_mean, g_std, gb0c, S, H0G);
  k_bias_corr<<<dim3(H0E / 64, E), dim3(64, 16), 0, stream>>>(eW0, eb0, e_mean, e_std, eb0c, S, H0E);

  constexpr size_t LDSCV = 5 * 128 * 64 * sizeof(f16);    // 80 KiB
  constexpr size_t LDS8P = 2 * 2 * 256 * 64 * sizeof(f16);  // 128 KiB

  // gating trunk + softmax head (proven counted-vmcnt 128^2 kernel)
  k_gemm_cv<<<dim3(H0G / 128, Bn / 128, 1), 256, LDSCV, stream>>>(
      xh, gW0t, gb0c, h0g, Bn, S, S, S, H0G, 0, 0, 0, 0);
  k_gemm_cv<<<dim3(H1G / 128, Bn / 128, 1), 256, LDSCV, stream>>>(
      h0g, gW1t, gb1, h1g, Bn, H0G, H0G, H0G, H1G, 0, 0, 0, 0);
  k_gating_head<<<Bn / 4, 256, 0, stream>>>(h1g, gWa, gba, gw, Bn);

  if (g == 4) {
    // expert L0: z=4, shared A (xh), 256^2 8-phase
    k_gemm_8p<<<dim3(H0E / 256, Bn / 256, 4), 512, LDS8P, stream>>>(
        xh, eW0t, eb0c, he0_g, Bn, S, S, S, H0E,
        0, (long)S * H0E, H0E, (long)Bn * H0E);
    // expert L1: z=4, K=1024 (unscaled; gw applied in k_head2)
    k_gemm_8p<<<dim3(H1E / 256, Bn / 256, 4), 512, LDS8P, stream>>>(
        he0_g, eW1t, eb1, he1_g, Bn, H0E, H0E, H0E, H1E,
        (long)Bn * H0E, (long)H0E * H1E, H1E, (long)Bn * H1E);
    // fused head over concat-K (4 x 512), writes out directly
    k_head2<<<dim3(Bn / 64), 256, 0, stream>>>(
        he1_g, eWat, eba, scale, gw, out, (long)Bn * H1E);
  } else {
    for (int e0 = 0; e0 < E; e0 += g) {
      k_gemm_cv<<<dim3(H0E / 128, Bn / 128, g), 256, LDSCV, stream>>>(
          xh, eW0t + (size_t)e0 * S * H0E, eb0c + (size_t)e0 * H0E, he0_g,
          Bn, S, S, S, H0E,
          0, (long)S * H0E, H0E, (long)Bn * H0E);
      k_gemm_cv<<<dim3(H1E / 128, Bn / 128, g), 256, LDSCV, stream>>>(
          he0_g, eW1t + (size_t)e0 * H0E * H1E, eb1 + (size_t)e0 * H1E, he1_g,
          Bn, H0E, H0E, H0E, H1E,
          (long)Bn * H0E, (long)H0E * H1E, H1E, (long)Bn * H1E);
      k_head<<<dim3(Bn / 64, 1, g), 256, 0, stream>>>(
          he1_g, eWat + (size_t)e0 * H1E * A, eba + (size_t)e0 * A, scale, gw,
          a_all + (size_t)e0 * Bn * A, e0, H1E,
          (long)Bn * H1E, (long)H1E * A, A, (long)Bn * A);
    }
    k_combine<<<(Bn * A) / 1024, 256, 0, stream>>>(a_all, out, (long)Bn * A);
  }
}